// Round 12
// baseline (344.046 us; speedup 1.0000x reference)
//
#include <hip/hip_runtime.h>
#include <hip/hip_bf16.h>
#include <stdint.h>

typedef __attribute__((ext_vector_type(8))) short v8s;
typedef __attribute__((ext_vector_type(4))) short v4s;
typedef __attribute__((ext_vector_type(4))) float v4f;

__device__ __forceinline__ short f2bf(float f) {
  union { float f; uint32_t u; } v; v.f = f;
  uint32_t u = v.u;
  uint32_t r = (u + 0x7fffu + ((u >> 16) & 1u)) >> 16;
  return (short)r;
}
__device__ __forceinline__ float bf2f(short s) {
  union { uint32_t u; float f; } v;
  v.u = ((uint32_t)(uint16_t)s) << 16;
  return v.f;
}
__device__ __forceinline__ void gload16(const void* g, void* l) {
  __builtin_amdgcn_global_load_lds(
      (const __attribute__((address_space(1))) void*)g,
      (__attribute__((address_space(3))) void*)l, 16, 0, 0);
}

// ---------- fused prep: 4 weight panels + 2 NHWC transposes + zp clear, one launch ----------
__global__ __launch_bounds__(256) void prep_fused_k(
    const float* __restrict__ wdef, const float* __restrict__ w1,
    const float* __restrict__ w2, const float* __restrict__ woff,
    const float* __restrict__ vit, const float* __restrict__ cnn,
    short* __restrict__ wdef_p, short* __restrict__ w1_p,
    short* __restrict__ w2_p, short* __restrict__ woff2_p,
    short* __restrict__ v_t, short* __restrict__ cnn_t,
    short* __restrict__ zp) {
  __shared__ float lds[32][65];
  int blk = blockIdx.x;
  int t = threadIdx.x;
  if (blk < 20736) {                       // wdef panels [864][768][8]
    int i = blk * 256 + t;
    int e = i & 7, o = (i >> 3) % 768, p = i / (8 * 768);
    int k = p * 8 + e, tap = k / 768, c = k % 768;
    wdef_p[i] = f2bf(wdef[((size_t)o * 768 + c) * 9 + tap]);
    return;
  }
  blk -= 20736;
  if (blk < 13824) {                       // w1 panels [864][512][8]
    int i = blk * 256 + t;
    int e = i & 7, o = (i >> 3) % 512, p = i / (8 * 512);
    int k = p * 8 + e, tap = k / 768, c = k % 768;
    w1_p[i] = f2bf(w1[((size_t)o * 768 + c) * 9 + tap]);
    return;
  }
  blk -= 13824;
  if (blk < 13824) {                       // w2 panels [576][768][8]
    int i = blk * 256 + t;
    int e = i & 7, o = (i >> 3) % 768, p = i / (8 * 768);
    int k = p * 8 + e, tap = k / 512, c = k % 512;
    w2_p[i] = f2bf(w2[((size_t)o * 512 + c) * 9 + tap]);
    return;
  }
  blk -= 13824;
  if (blk < 2880) {                        // woff2 panels [480][192][8]
    int i = blk * 256 + t;
    int e = i & 7, m = (i >> 3) % 192, kp = i / 1536;
    int c = kp * 8 + e, o = m / 9, tap = m % 9;
    woff2_p[i] = (m < 162) ? f2bf(woff[((size_t)o * 3840 + c) * 9 + tap]) : (short)0;
    return;
  }
  blk -= 2880;
  if (blk >= 3000 + 2352) {                // zp clear (256 bytes)
    if (t < 128) zp[t] = 0;
    return;
  }
  const float* in; short* out; int C, P, bx, by;
  if (blk < 3000) { in = vit; out = v_t; C = 3840; P = 196; bx = blk % 25; by = blk / 25; }
  else { blk -= 3000; in = cnn; out = cnn_t; C = 768; P = 784; bx = blk % 98; by = blk / 98; }
  int n0 = bx * 64, c0 = by * 32;
#pragma unroll
  for (int e = 0; e < 8; e++) {
    int id = e * 256 + t;
    int cl = id >> 6, nl = id & 63;
    int n = n0 + nl;
    if (n < 8 * P) {
      int b = n / P, p = n % P;
      lds[cl][nl] = in[((size_t)b * C + c0 + cl) * P + p];
    }
  }
  __syncthreads();
  int nl = t >> 2, cs = (t & 3) * 8;
  int n = n0 + nl;
  if (n < 8 * P) {
    v8s v;
#pragma unroll
    for (int i = 0; i < 8; i++) v[i] = f2bf(lds[cs + i][nl]);
    *(v8s*)(out + (size_t)n * C + c0 + cs) = v;
  }
}

// ---------- deform GEMM: A in registers (L2-direct, double-buffered), B via LDS ----------
// 128x64 tile, 588 blocks, bijective XCD swizzle, m-fastest. LDS = 16 KB (B only).
__global__ __launch_bounds__(256) void deform_gemm_k(const short* __restrict__ Ap,
                                                     const short* __restrict__ Bp,
                                                     const float* __restrict__ bias,
                                                     short* __restrict__ d_t) {
  constexpr int NT = 108;
  __shared__ __align__(16) short SMB[2][512 * 8];   // [kg(8)][col(64)][8] per buf

  const int tid = threadIdx.x;
  const int lane = tid & 63, wid = tid >> 6;
  const int wm = wid >> 1, wn = wid & 1;
  int bid = blockIdx.y * 98 + blockIdx.x;
  int xcd = bid & 7, idx = bid >> 3;
  constexpr int q = 73, r = 4;
  int wg = (xcd < r ? xcd * (q + 1) : r * (q + 1) + (xcd - r) * q) + idx;
  const int by = wg % 6, bx = wg / 6;
  const int n0 = bx * 64, m0 = by * 128;
  const int lrow = lane & 15, lkg = lane >> 4;
  const int arow = m0 + wm * 64 + lrow;

  v4f acc[4][2];
#pragma unroll
  for (int i = 0; i < 4; i++)
#pragma unroll
    for (int j = 0; j < 2; j++) acc[i][j] = (v4f){0.f, 0.f, 0.f, 0.f};

  v8s afA[2][4], afB[2][4];

  auto loadA = [&](int k, v8s a[2][4]) {
#pragma unroll
    for (int s = 0; s < 2; s++)
#pragma unroll
      for (int mf = 0; mf < 4; mf++)
        a[s][mf] = *(const v8s*)(Ap + ((size_t)((k >> 3) + s * 4 + lkg) * 768 + arow + mf * 16) * 8);
  };
  auto stageB = [&](int k, int buf) {
#pragma unroll
    for (int it = 0; it < 2; it++) {
      int ch = it * 256 + tid;
      int kg = ch >> 6, col = ch & 63;
      gload16(Bp + ((size_t)((k >> 3) + kg) * 6272 + n0 + col) * 8,
              &SMB[buf][(size_t)(it * 256 + (tid & ~63)) * 8]);
    }
  };
  auto compute = [&](int buf, v8s a[2][4]) {
    v8s bf[2][2];
#pragma unroll
    for (int s = 0; s < 2; s++)
#pragma unroll
      for (int nf = 0; nf < 2; nf++)
        bf[s][nf] = *(const v8s*)(&SMB[buf][(size_t)((s * 4 + lkg) * 64 + wn * 32 + nf * 16 + lrow) * 8]);
#pragma unroll
    for (int s = 0; s < 2; s++)
#pragma unroll
      for (int mf = 0; mf < 4; mf++)
#pragma unroll
        for (int nf = 0; nf < 2; nf++)
          acc[mf][nf] = __builtin_amdgcn_mfma_f32_16x16x32_bf16(a[s][mf], bf[s][nf], acc[mf][nf], 0, 0, 0);
  };

  loadA(0, afA);
  stageB(0, 0);
  __syncthreads();
  for (int t = 0; t < NT; t += 2) {
    // body A: uses buf 0 / afA; prefetch t+1 into buf 1 / afB
    stageB((t + 1) * 64, 1);
    loadA((t + 1) * 64, afB);
    compute(0, afA);
    __syncthreads();
    // body B: uses buf 1 / afB; prefetch t+2 into buf 0 / afA
    if (t + 2 < NT) {
      stageB((t + 2) * 64, 0);
      loadA((t + 2) * 64, afA);
    }
    compute(1, afB);
    __syncthreads();
  }

#pragma unroll
  for (int mf = 0; mf < 4; mf++) {
    int gm = m0 + wm * 64 + mf * 16 + lkg * 4;
#pragma unroll
    for (int nf = 0; nf < 2; nf++) {
      int gn = n0 + wn * 32 + nf * 16 + lrow;
      v4f a4 = acc[mf][nf];
      v4s v;
#pragma unroll
      for (int rr = 0; rr < 4; rr++) v[rr] = f2bf(a4[rr] + bias[gm + rr]);
      *(v4s*)(d_t + (size_t)gn * 768 + gm) = v;
    }
  }
}

// ---------- generic GEMM (modes 0/2/3): BK=64, double-buffered, gload_lds staging ----------
template<int MODE, int BM, int BN, int WGM, int AO, int CIN, int KSPLIT,
         int NVALID, int IH, int IW, int OW, int STRIDE, int PART>
__global__ __launch_bounds__(256) void gemm_k(const short* __restrict__ Ap,
                                              const short* __restrict__ Bp,
                                              const float* __restrict__ bias,
                                              void* __restrict__ dst,
                                              const short* __restrict__ zp) {
  constexpr int WGN = 4 / WGM;
  constexpr int WM = BM / WGM, WN = BN / WGN;
  constexpr int MF = WM / 16, NF = WN / 16;
  constexpr int CHA = BM * 8, CHT = (BM + BN) * 8;
  constexpr int NT = KSPLIT / 64;

  __shared__ __align__(16) short SM[2][CHT * 8];

  const int tid = threadIdx.x;
  const int lane = tid & 63, wid = tid >> 6;
  const int wm = wid / WGN, wn = wid % WGN;
  const int n0 = blockIdx.x * BN, m0 = blockIdx.y * BM;
  const int ts = blockIdx.z;
  const int kbeg = ts * KSPLIT;
  const int lrow = lane & 15, lkg = lane >> 4;

  v4f acc[MF][NF];
#pragma unroll
  for (int i = 0; i < MF; i++)
#pragma unroll
    for (int j = 0; j < NF; j++) acc[i][j] = (v4f){0.f, 0.f, 0.f, 0.f};

  auto stage = [&](int k, int buf) {
#pragma unroll
    for (int it = 0; it < CHT / 256; it++) {
      int ch = it * 256 + tid;
      const short* src;
      if (ch < CHA) {
        int kg = ch / BM, row = ch % BM;
        src = Ap + ((size_t)((k >> 3) + kg) * AO + m0 + row) * 8;
      } else {
        int bch = ch - CHA;
        int kg = bch / BN, col = bch % BN;
        int gk = k + kg * 8;
        int n = n0 + col;
        if constexpr (MODE == 0) {
          src = (n < NVALID) ? Bp + ((size_t)n * 3840 + gk) : zp;
        } else {
          int tap = gk / CIN, cc = gk % CIN;
          int b = n / (OW * OW), rem = n % (OW * OW);
          int oy = rem / OW, ox = rem % OW;
          int py = oy * STRIDE + tap / 3 - 1, px = ox * STRIDE + tap % 3 - 1;
          src = (n < NVALID && py >= 0 && py < IH && px >= 0 && px < IW)
                  ? Bp + ((size_t)((b * IH + py) * IW + px) * CIN + cc)
                  : zp;
        }
      }
      gload16(src, &SM[buf][(size_t)(it * 256 + (tid & ~63)) * 8]);
    }
  };

  stage(kbeg, 0);
  __syncthreads();
  int buf = 0;
  for (int t = 0; t < NT; ++t) {
    if (t + 1 < NT) stage(kbeg + (t + 1) * 64, buf ^ 1);
    v8s af[2][MF], bfv[2][NF];
#pragma unroll
    for (int s = 0; s < 2; s++) {
#pragma unroll
      for (int mf = 0; mf < MF; mf++)
        af[s][mf] = *(const v8s*)(&SM[buf][(size_t)((s * 4 + lkg) * BM + wm * WM + mf * 16 + lrow) * 8]);
#pragma unroll
      for (int nf = 0; nf < NF; nf++)
        bfv[s][nf] = *(const v8s*)(&SM[buf][(size_t)(CHA + (s * 4 + lkg) * BN + wn * WN + nf * 16 + lrow) * 8]);
    }
#pragma unroll
    for (int s = 0; s < 2; s++)
#pragma unroll
      for (int mf = 0; mf < MF; mf++)
#pragma unroll
        for (int nf = 0; nf < NF; nf++)
          acc[mf][nf] = __builtin_amdgcn_mfma_f32_16x16x32_bf16(af[s][mf], bfv[s][nf], acc[mf][nf], 0, 0, 0);
    __syncthreads();
    buf ^= 1;
  }

#pragma unroll
  for (int mf = 0; mf < MF; mf++) {
    int gm = m0 + wm * WM + mf * 16 + lkg * 4;
#pragma unroll
    for (int nf = 0; nf < NF; nf++) {
      int gn = n0 + wn * WN + nf * 16 + lrow;
      v4f a4 = acc[mf][nf];
      if constexpr (MODE == 0) {
        float* part = (float*)dst;
        if (gn < NVALID) {
#pragma unroll
          for (int r = 0; r < 4; r++)
            part[((size_t)ts * AO + gm + r) * 1568 + gn] = a4[r];
        }
      } else if constexpr (MODE == 2) {
        if (gn < NVALID) {
          if constexpr (PART) {
            float* pd = (float*)dst;
            *(v4f*)(pd + ((size_t)ts * 1568 + gn) * 512 + gm) = a4;
          } else {
            short* ht = (short*)dst;
            v4s v;
#pragma unroll
            for (int r = 0; r < 4; r++) v[r] = f2bf(fmaxf(a4[r] + bias[gm + r], 0.f));
            *(v4s*)(ht + (size_t)gn * 512 + gm) = v;
          }
        }
      } else {
        if (gn < NVALID) {
          if constexpr (PART) {
            float* pd = (float*)dst;
#pragma unroll
            for (int r = 0; r < 4; r++)
              pd[((size_t)(ts * 768) + gm + r) * 1568 + gn] = a4[r];
          } else {
            float* o = (float*)dst;
            int b = gn / 196, p = gn % 196;
#pragma unroll
            for (int r = 0; r < 4; r++)
              o[((size_t)(b * 768 + gm + r)) * 196 + p] = a4[r] + bias[gm + r];
          }
        }
      }
    }
  }
}

// ---------- offset gather-reduce: offs[b][18][28][28] from q partials ----------
__global__ __launch_bounds__(256) void reduce_off2_k(const float* __restrict__ part,
                                                     const float* __restrict__ boff,
                                                     float* __restrict__ offs) {
  int i = blockIdx.x * 256 + threadIdx.x;
  if (i >= 8 * 18 * 784) return;
  int b = i / (18 * 784), r = i % (18 * 784);
  int o = r / 784, yx = r % 784;
  int y = yx / 28, x = yx % 28;
  float s = boff[o];
#pragma unroll
  for (int tap = 0; tap < 9; tap++) {
    int py = y + tap / 3 - 1, px = x + tap % 3 - 1;
    if (py >= 0 && py < 28 && px >= 0 && px < 28) {
      int n = b * 196 + (py >> 1) * 14 + (px >> 1);
      int m = o * 9 + tap;
#pragma unroll
      for (int z = 0; z < 4; z++)
        s += part[((size_t)z * 192 + m) * 1568 + n];
    }
  }
  offs[i] = s;
}

// ---------- conv1 split-K reduce ----------
__global__ __launch_bounds__(256) void reduce_c1_k(const float* __restrict__ part,
                                                   const float* __restrict__ b1,
                                                   short* __restrict__ h_t) {
  int i = blockIdx.x * 256 + threadIdx.x;
  if (i >= 1568 * 128) return;
  int n = i >> 7, o4 = (i & 127) * 4;
  v4f s0 = *(const v4f*)(part + ((size_t)n) * 512 + o4);
  v4f s1 = *(const v4f*)(part + ((size_t)(1568 + n)) * 512 + o4);
  v4f bb = *(const v4f*)(b1 + o4);
  v4s v;
#pragma unroll
  for (int r = 0; r < 4; r++) v[r] = f2bf(fmaxf(s0[r] + s1[r] + bb[r], 0.f));
  *(v4s*)(h_t + (size_t)n * 512 + o4) = v;
}

// ---------- conv2 split-K reduce ----------
__global__ __launch_bounds__(256) void reduce_c2_k(const float* __restrict__ part,
                                                   const float* __restrict__ b2,
                                                   float* __restrict__ out) {
  int i = blockIdx.x * 256 + threadIdx.x;
  if (i >= 768 * 392) return;
  int m = i / 392, n4 = (i % 392) * 4;
  v4f s0 = *(const v4f*)(part + (size_t)m * 1568 + n4);
  v4f s1 = *(const v4f*)(part + (size_t)(768 + m) * 1568 + n4);
  float bv = b2[m];
  int b = n4 / 196, p = n4 % 196;
  v4f o;
#pragma unroll
  for (int r = 0; r < 4; r++) o[r] = s0[r] + s1[r] + bv;
  *(v4f*)(out + ((size_t)(b * 768 + m)) * 196 + p) = o;
}

// ---------- bilinear sampling: batch-pinned XCD + full TLP (r11 proven) ----------
__global__ __launch_bounds__(256) void sample_k(const short* __restrict__ cnn_t,
                                                const float* __restrict__ offs,
                                                short* __restrict__ sp) {
  int bid = blockIdx.x;
  int b = bid & 7;
  int r = bid >> 3;
  int tap = r >> 5;
  int rr = r & 31;
  int cg = rr >> 2, pg = rr & 3;
  int t = threadIdx.x;
  if (t >= 196) return;
  int yx = pg * 196 + t;
  int y = yx / 28, x = yx % 28;
  float dy = offs[((size_t)b * 18 + tap * 2 + 0) * 784 + yx];
  float dx = offs[((size_t)b * 18 + tap * 2 + 1) * 784 + yx];
  float py = (float)(y + tap / 3 - 1) + dy;
  float px = (float)(x + tap % 3 - 1) + dx;
  float fy = floorf(py), fx = floorf(px);
  float ly = py - fy, lx = px - fx;
  int y0 = (int)fy, x0 = (int)fx;
  int y1 = y0 + 1, x1 = x0 + 1;
  float vy0 = (y0 >= 0 && y0 < 28) ? 1.f : 0.f;
  float vy1 = (y1 >= 0 && y1 < 28) ? 1.f : 0.f;
  float vx0 = (x0 >= 0 && x0 < 28) ? 1.f : 0.f;
  float vx1 = (x1 >= 0 && x1 < 28) ? 1.f : 0.f;
  float w00 = (1.f - ly) * (1.f - lx) * vy0 * vx0;
  float w01 = (1.f - ly) * lx * vy0 * vx1;
  float w10 = ly * (1.f - lx) * vy1 * vx0;
  float w11 = ly * lx * vy1 * vx1;
  int cy0 = min(max(y0, 0), 27), cy1 = min(max(y1, 0), 27);
  int cx0 = min(max(x0, 0), 27), cx1 = min(max(x1, 0), 27);
  int c0 = cg * 12;
  const short* base = cnn_t + (size_t)b * 784 * 768 + c0 * 8;
  const short* p00 = base + (size_t)(cy0 * 28 + cx0) * 768;
  const short* p01 = base + (size_t)(cy0 * 28 + cx1) * 768;
  const short* p10 = base + (size_t)(cy1 * 28 + cx0) * 768;
  const short* p11 = base + (size_t)(cy1 * 28 + cx1) * 768;
  short* op = sp + ((size_t)(tap * 96 + c0) * 6272 + b * 784 + yx) * 8;
#pragma unroll 4
  for (int i = 0; i < 12; ++i) {
    v8s a = *(const v8s*)(p00 + i * 8);
    v8s bb = *(const v8s*)(p01 + i * 8);
    v8s c = *(const v8s*)(p10 + i * 8);
    v8s d = *(const v8s*)(p11 + i * 8);
    v8s o;
#pragma unroll
    for (int j = 0; j < 8; j++) {
      float v = w00 * bf2f(a[j]) + w01 * bf2f(bb[j]) + w10 * bf2f(c[j]) + w11 * bf2f(d[j]);
      o[j] = f2bf(v);
    }
    *(v8s*)op = o;
    op += (size_t)6272 * 8;
  }
}

// ---------- launch ----------
extern "C" void kernel_launch(void* const* d_in, const int* in_sizes, int n_in,
                              void* d_out, int out_size, void* d_ws, size_t ws_size,
                              hipStream_t stream) {
  const float* cnn   = (const float*)d_in[0];
  const float* vit   = (const float*)d_in[1];
  const float* w_off = (const float*)d_in[2];
  const float* b_off = (const float*)d_in[3];
  const float* w_def = (const float*)d_in[4];
  const float* b_def = (const float*)d_in[5];
  const float* w1    = (const float*)d_in[6];
  const float* b1    = (const float*)d_in[7];
  const float* w2    = (const float*)d_in[8];
  const float* b2    = (const float*)d_in[9];
  float* out = (float*)d_out;
  char* ws = (char*)d_ws;

  short* wdef_p  = (short*)(ws + 0);          // 10,616,832
  short* w1_p    = (short*)(ws + 10616832);   //  7,077,888
  short* w2_p    = (short*)(ws + 17694720);   //  7,077,888
  short* woff2_p = (short*)(ws + 24772608);   //  1,474,560
  short* v_t     = (short*)(ws + 26247168);   // 12,042,240
  float* offs    = (float*)(ws + 38289408);   //    451,584
  float* part    = (float*)(ws + 38740992);   //  4,816,896 (dead after reduce_off2)
  short* sp      = (short*)(ws + 38740992);   // 86,704,128 (aliases part; dead after deform)
  float* part1   = (float*)(ws + 38740992);   //  6,422,528 (aliases sp; conv1 partials)
  float* part2   = (float*)(ws + 45163520);   //  9,633,792 (conv2 partials)
  short* d_t     = (short*)(ws + 125445120);  //  9,633,792
  short* h_t     = (short*)(ws + 135078912);  //  1,605,632
  short* cnn_t   = (short*)(ws + 136684544);  //  9,633,792
  short* zp      = (short*)(ws + 146318336);  // 256 zero page
  // total 146,318,592 bytes

  dim3 blk(256);
  // fused weight preps + NHWC transposes + zp clear (one launch, 56,617 blocks)
  prep_fused_k<<<56617, blk, 0, stream>>>(w_def, w1, w2, w_off, vit, cnn,
                                          wdef_p, w1_p, w2_p, woff2_p, v_t, cnn_t, zp);

  // offset q-GEMM: q[o*9+tap][n14], split-K x4 -> partials
  gemm_k<0, 64, 64, 2, 192, 3840, 960, 1568, 14, 14, 14, 1, 0>
      <<<dim3(25, 3, 4), blk, 0, stream>>>(woff2_p, v_t, nullptr, part, zp);
  // gather-reduce -> offs[b][18][28][28]
  reduce_off2_k<<<441, blk, 0, stream>>>(part, b_off, offs);

  // bilinear sampling -> sp panels (batch-pinned XCD, 2304 blocks)
  sample_k<<<2304, blk, 0, stream>>>(cnn_t, offs, sp);

  // deformable conv GEMM -> d_t (NHWC bf16): A-in-registers, B-in-LDS
  deform_gemm_k<<<dim3(98, 6), blk, 0, stream>>>(wdef_p, sp, b_def, d_t);

  // conv1 stride 2, split-K x2 -> fp32 partials -> reduce(+bias+relu) -> h_t
  gemm_k<2, 64, 64, 2, 512, 768, 3456, 1568, 28, 28, 14, 2, 1>
      <<<dim3(25, 8, 2), blk, 0, stream>>>(w1_p, d_t, b1, part1, zp);
  reduce_c1_k<<<784, blk, 0, stream>>>(part1, b1, h_t);

  // conv2 split-K x2 -> fp32 partials -> reduce(+bias) -> out
  gemm_k<3, 64, 64, 2, 768, 512, 2304, 1568, 14, 14, 14, 1, 1>
      <<<dim3(25, 12, 2), blk, 0, stream>>>(w2_p, h_t, b2, part2, zp);
  reduce_c2_k<<<1176, blk, 0, stream>>>(part2, b2, out);
}

// Round 13
// 277.932 us; speedup vs baseline: 1.2379x; 1.2379x over previous
//
#include <hip/hip_runtime.h>
#include <hip/hip_bf16.h>
#include <stdint.h>

typedef __attribute__((ext_vector_type(8))) short v8s;
typedef __attribute__((ext_vector_type(4))) short v4s;
typedef __attribute__((ext_vector_type(4))) float v4f;

__device__ __forceinline__ short f2bf(float f) {
  union { float f; uint32_t u; } v; v.f = f;
  uint32_t u = v.u;
  uint32_t r = (u + 0x7fffu + ((u >> 16) & 1u)) >> 16;
  return (short)r;
}
__device__ __forceinline__ float bf2f(short s) {
  union { uint32_t u; float f; } v;
  v.u = ((uint32_t)(uint16_t)s) << 16;
  return v.f;
}
__device__ __forceinline__ void gload16(const void* g, void* l) {
  __builtin_amdgcn_global_load_lds(
      (const __attribute__((address_space(1))) void*)g,
      (__attribute__((address_space(3))) void*)l, 16, 0, 0);
}

// ---------- fused prep: 4 weight panels + 2 NHWC transposes + zp clear, one launch ----------
__global__ __launch_bounds__(256) void prep_fused_k(
    const float* __restrict__ wdef, const float* __restrict__ w1,
    const float* __restrict__ w2, const float* __restrict__ woff,
    const float* __restrict__ vit, const float* __restrict__ cnn,
    short* __restrict__ wdef_p, short* __restrict__ w1_p,
    short* __restrict__ w2_p, short* __restrict__ woff2_p,
    short* __restrict__ v_t, short* __restrict__ cnn_t,
    short* __restrict__ zp) {
  __shared__ float lds[32][65];
  int blk = blockIdx.x;
  int t = threadIdx.x;
  if (blk < 20736) {                       // wdef panels [864][768][8]
    int i = blk * 256 + t;
    int e = i & 7, o = (i >> 3) % 768, p = i / (8 * 768);
    int k = p * 8 + e, tap = k / 768, c = k % 768;
    wdef_p[i] = f2bf(wdef[((size_t)o * 768 + c) * 9 + tap]);
    return;
  }
  blk -= 20736;
  if (blk < 13824) {                       // w1 panels [864][512][8]
    int i = blk * 256 + t;
    int e = i & 7, o = (i >> 3) % 512, p = i / (8 * 512);
    int k = p * 8 + e, tap = k / 768, c = k % 768;
    w1_p[i] = f2bf(w1[((size_t)o * 768 + c) * 9 + tap]);
    return;
  }
  blk -= 13824;
  if (blk < 13824) {                       // w2 panels [576][768][8]
    int i = blk * 256 + t;
    int e = i & 7, o = (i >> 3) % 768, p = i / (8 * 768);
    int k = p * 8 + e, tap = k / 512, c = k % 512;
    w2_p[i] = f2bf(w2[((size_t)o * 512 + c) * 9 + tap]);
    return;
  }
  blk -= 13824;
  if (blk < 2880) {                        // woff2 panels [480][192][8]
    int i = blk * 256 + t;
    int e = i & 7, m = (i >> 3) % 192, kp = i / 1536;
    int c = kp * 8 + e, o = m / 9, tap = m % 9;
    woff2_p[i] = (m < 162) ? f2bf(woff[((size_t)o * 3840 + c) * 9 + tap]) : (short)0;
    return;
  }
  blk -= 2880;
  if (blk >= 3000 + 2352) {                // zp clear (256 bytes)
    if (t < 128) zp[t] = 0;
    return;
  }
  const float* in; short* out; int C, P, bx, by;
  if (blk < 3000) { in = vit; out = v_t; C = 3840; P = 196; bx = blk % 25; by = blk / 25; }
  else { blk -= 3000; in = cnn; out = cnn_t; C = 768; P = 784; bx = blk % 98; by = blk / 98; }
  int n0 = bx * 64, c0 = by * 32;
#pragma unroll
  for (int e = 0; e < 8; e++) {
    int id = e * 256 + t;
    int cl = id >> 6, nl = id & 63;
    int n = n0 + nl;
    if (n < 8 * P) {
      int b = n / P, p = n % P;
      lds[cl][nl] = in[((size_t)b * C + c0 + cl) * P + p];
    }
  }
  __syncthreads();
  int nl = t >> 2, cs = (t & 3) * 8;
  int n = n0 + nl;
  if (n < 8 * P) {
    v8s v;
#pragma unroll
    for (int i = 0; i < 8; i++) v[i] = f2bf(lds[cs + i][nl]);
    *(v8s*)(out + (size_t)n * C + c0 + cs) = v;
  }
}

// ---------- GEMM: BK=64, double-buffered prefetch, gload_lds staging (r6/r11 proven) ----------
// MODE 0: offset q-GEMM (B = v_t direct, dst fp32 partials, split-K)
// MODE 1: deform GEMM  (B = sp panels, dst NHWC bf16 +bias), 128x64, 588 blocks
// MODE 2: conv1 s2 (B = im2col(d_t); PART: fp32 NHWC partials), XCD m-fastest swizzle
// MODE 3: conv2 (B = im2col(h_t); PART: fp32 [z][768][1568] partials)
template<int MODE, int BM, int BN, int WGM, int AO, int CIN, int KSPLIT,
         int NVALID, int IH, int IW, int OW, int STRIDE, int PART>
__global__ __launch_bounds__(256) void gemm_k(const short* __restrict__ Ap,
                                              const short* __restrict__ Bp,
                                              const float* __restrict__ bias,
                                              void* __restrict__ dst,
                                              const short* __restrict__ zp) {
  constexpr int WGN = 4 / WGM;
  constexpr int WM = BM / WGM, WN = BN / WGN;
  constexpr int MF = WM / 16, NF = WN / 16;
  constexpr int CHA = BM * 8, CHT = (BM + BN) * 8;
  constexpr int NT = KSPLIT / 64;

  __shared__ __align__(16) short SM[2][CHT * 8];

  const int tid = threadIdx.x;
  const int lane = tid & 63, wid = tid >> 6;
  const int wm = wid / WGN, wn = wid % WGN;
  int bx = blockIdx.x, by = blockIdx.y;
  if constexpr (MODE == 1) {
    // bijective XCD swizzle, nwg = 588 = 8*73 + 4; m-fastest within XCD chunk
    int bid = by * 98 + bx;
    int xcd = bid & 7, idx = bid >> 3;
    constexpr int q = 73, r = 4;
    int wg = (xcd < r ? xcd * (q + 1) : r * (q + 1) + (xcd - r) * q) + idx;
    by = wg % 6; bx = wg / 6;
  }
  if constexpr (MODE == 2) {
    // 200 blocks per z-slice = 8*25 exact; m-fastest so the 8 m-tiles sharing a
    // d_t gather window are consecutive on one XCD (L2 reuse).
    int bid = by * 25 + bx;
    int swz = (bid & 7) * 25 + (bid >> 3);
    by = swz % 8; bx = swz / 8;
  }
  const int n0 = bx * BN, m0 = by * BM;
  const int ts = blockIdx.z;
  const int kbeg = ts * KSPLIT;
  const int lrow = lane & 15, lkg = lane >> 4;

  v4f acc[MF][NF];
#pragma unroll
  for (int i = 0; i < MF; i++)
#pragma unroll
    for (int j = 0; j < NF; j++) acc[i][j] = (v4f){0.f, 0.f, 0.f, 0.f};

  auto stage = [&](int k, int buf) {
#pragma unroll
    for (int it = 0; it < CHT / 256; it++) {
      int ch = it * 256 + tid;
      const short* src;
      if (ch < CHA) {
        int kg = ch / BM, row = ch % BM;
        src = Ap + ((size_t)((k >> 3) + kg) * AO + m0 + row) * 8;
      } else {
        int bch = ch - CHA;
        int kg = bch / BN, col = bch % BN;
        int gk = k + kg * 8;
        int n = n0 + col;
        if constexpr (MODE == 0) {
          src = (n < NVALID) ? Bp + ((size_t)n * 3840 + gk) : zp;
        } else if constexpr (MODE == 1) {
          src = Bp + ((size_t)(gk >> 3) * 6272 + n) * 8;
        } else {
          int tap = gk / CIN, cc = gk % CIN;
          int b = n / (OW * OW), rem = n % (OW * OW);
          int oy = rem / OW, ox = rem % OW;
          int py = oy * STRIDE + tap / 3 - 1, px = ox * STRIDE + tap % 3 - 1;
          src = (n < NVALID && py >= 0 && py < IH && px >= 0 && px < IW)
                  ? Bp + ((size_t)((b * IH + py) * IW + px) * CIN + cc)
                  : zp;
        }
      }
      gload16(src, &SM[buf][(size_t)(it * 256 + (tid & ~63)) * 8]);
    }
  };

  stage(kbeg, 0);
  __syncthreads();
  int buf = 0;
  for (int t = 0; t < NT; ++t) {
    if (t + 1 < NT) stage(kbeg + (t + 1) * 64, buf ^ 1);
    v8s af[2][MF], bfv[2][NF];
#pragma unroll
    for (int s = 0; s < 2; s++) {
#pragma unroll
      for (int mf = 0; mf < MF; mf++)
        af[s][mf] = *(const v8s*)(&SM[buf][(size_t)((s * 4 + lkg) * BM + wm * WM + mf * 16 + lrow) * 8]);
#pragma unroll
      for (int nf = 0; nf < NF; nf++)
        bfv[s][nf] = *(const v8s*)(&SM[buf][(size_t)(CHA + (s * 4 + lkg) * BN + wn * WN + nf * 16 + lrow) * 8]);
    }
#pragma unroll
    for (int s = 0; s < 2; s++)
#pragma unroll
      for (int mf = 0; mf < MF; mf++)
#pragma unroll
        for (int nf = 0; nf < NF; nf++)
          acc[mf][nf] = __builtin_amdgcn_mfma_f32_16x16x32_bf16(af[s][mf], bfv[s][nf], acc[mf][nf], 0, 0, 0);
    __syncthreads();
    buf ^= 1;
  }

#pragma unroll
  for (int mf = 0; mf < MF; mf++) {
    int gm = m0 + wm * WM + mf * 16 + lkg * 4;
#pragma unroll
    for (int nf = 0; nf < NF; nf++) {
      int gn = n0 + wn * WN + nf * 16 + lrow;
      v4f a4 = acc[mf][nf];
      if constexpr (MODE == 0) {
        float* part = (float*)dst;
        if (gn < NVALID) {
#pragma unroll
          for (int r = 0; r < 4; r++)
            part[((size_t)ts * AO + gm + r) * 1568 + gn] = a4[r];
        }
      } else if constexpr (MODE == 1) {
        short* dt = (short*)dst;
        v4s v;
#pragma unroll
        for (int r = 0; r < 4; r++) v[r] = f2bf(a4[r] + bias[gm + r]);
        *(v4s*)(dt + (size_t)gn * 768 + gm) = v;
      } else if constexpr (MODE == 2) {
        if (gn < NVALID) {
          if constexpr (PART) {
            float* pd = (float*)dst;
            *(v4f*)(pd + ((size_t)ts * 1568 + gn) * 512 + gm) = a4;
          } else {
            short* ht = (short*)dst;
            v4s v;
#pragma unroll
            for (int r = 0; r < 4; r++) v[r] = f2bf(fmaxf(a4[r] + bias[gm + r], 0.f));
            *(v4s*)(ht + (size_t)gn * 512 + gm) = v;
          }
        }
      } else {
        if (gn < NVALID) {
          if constexpr (PART) {
            float* pd = (float*)dst;
#pragma unroll
            for (int r = 0; r < 4; r++)
              pd[((size_t)(ts * 768) + gm + r) * 1568 + gn] = a4[r];
          } else {
            float* o = (float*)dst;
            int b = gn / 196, p = gn % 196;
#pragma unroll
            for (int r = 0; r < 4; r++)
              o[((size_t)(b * 768 + gm + r)) * 196 + p] = a4[r] + bias[gm + r];
          }
        }
      }
    }
  }
}

// ---------- offset gather-reduce: offs[b][18][28][28] from q partials ----------
__global__ __launch_bounds__(256) void reduce_off2_k(const float* __restrict__ part,
                                                     const float* __restrict__ boff,
                                                     float* __restrict__ offs) {
  int i = blockIdx.x * 256 + threadIdx.x;
  if (i >= 8 * 18 * 784) return;
  int b = i / (18 * 784), r = i % (18 * 784);
  int o = r / 784, yx = r % 784;
  int y = yx / 28, x = yx % 28;
  float s = boff[o];
#pragma unroll
  for (int tap = 0; tap < 9; tap++) {
    int py = y + tap / 3 - 1, px = x + tap % 3 - 1;
    if (py >= 0 && py < 28 && px >= 0 && px < 28) {
      int n = b * 196 + (py >> 1) * 14 + (px >> 1);
      int m = o * 9 + tap;
#pragma unroll
      for (int z = 0; z < 4; z++)
        s += part[((size_t)z * 192 + m) * 1568 + n];
    }
  }
  offs[i] = s;
}

// ---------- conv1 split-K reduce: partials [2][1568][512] -> h_t NHWC bf16 (+bias, relu) ----------
__global__ __launch_bounds__(256) void reduce_c1_k(const float* __restrict__ part,
                                                   const float* __restrict__ b1,
                                                   short* __restrict__ h_t) {
  int i = blockIdx.x * 256 + threadIdx.x;
  if (i >= 1568 * 128) return;
  int n = i >> 7, o4 = (i & 127) * 4;
  v4f s0 = *(const v4f*)(part + ((size_t)n) * 512 + o4);
  v4f s1 = *(const v4f*)(part + ((size_t)(1568 + n)) * 512 + o4);
  v4f bb = *(const v4f*)(b1 + o4);
  v4s v;
#pragma unroll
  for (int r = 0; r < 4; r++) v[r] = f2bf(fmaxf(s0[r] + s1[r] + bb[r], 0.f));
  *(v4s*)(h_t + (size_t)n * 512 + o4) = v;
}

// ---------- conv2 split-K reduce: partials [2][768][1568] -> out fp32 NCHW (+bias) ----------
__global__ __launch_bounds__(256) void reduce_c2_k(const float* __restrict__ part,
                                                   const float* __restrict__ b2,
                                                   float* __restrict__ out) {
  int i = blockIdx.x * 256 + threadIdx.x;
  if (i >= 768 * 392) return;
  int m = i / 392, n4 = (i % 392) * 4;
  v4f s0 = *(const v4f*)(part + (size_t)m * 1568 + n4);
  v4f s1 = *(const v4f*)(part + (size_t)(768 + m) * 1568 + n4);
  float bv = b2[m];
  int b = n4 / 196, p = n4 % 196;
  v4f o;
#pragma unroll
  for (int r = 0; r < 4; r++) o[r] = s0[r] + s1[r] + bv;
  *(v4f*)(out + ((size_t)(b * 768 + m)) * 196 + p) = o;
}

// ---------- bilinear sampling: batch-pinned XCD + full TLP (r11 proven) ----------
__global__ __launch_bounds__(256) void sample_k(const short* __restrict__ cnn_t,
                                                const float* __restrict__ offs,
                                                short* __restrict__ sp) {
  int bid = blockIdx.x;
  int b = bid & 7;
  int r = bid >> 3;
  int tap = r >> 5;
  int rr = r & 31;
  int cg = rr >> 2, pg = rr & 3;
  int t = threadIdx.x;
  if (t >= 196) return;
  int yx = pg * 196 + t;
  int y = yx / 28, x = yx % 28;
  float dy = offs[((size_t)b * 18 + tap * 2 + 0) * 784 + yx];
  float dx = offs[((size_t)b * 18 + tap * 2 + 1) * 784 + yx];
  float py = (float)(y + tap / 3 - 1) + dy;
  float px = (float)(x + tap % 3 - 1) + dx;
  float fy = floorf(py), fx = floorf(px);
  float ly = py - fy, lx = px - fx;
  int y0 = (int)fy, x0 = (int)fx;
  int y1 = y0 + 1, x1 = x0 + 1;
  float vy0 = (y0 >= 0 && y0 < 28) ? 1.f : 0.f;
  float vy1 = (y1 >= 0 && y1 < 28) ? 1.f : 0.f;
  float vx0 = (x0 >= 0 && x0 < 28) ? 1.f : 0.f;
  float vx1 = (x1 >= 0 && x1 < 28) ? 1.f : 0.f;
  float w00 = (1.f - ly) * (1.f - lx) * vy0 * vx0;
  float w01 = (1.f - ly) * lx * vy0 * vx1;
  float w10 = ly * (1.f - lx) * vy1 * vx0;
  float w11 = ly * lx * vy1 * vx1;
  int cy0 = min(max(y0, 0), 27), cy1 = min(max(y1, 0), 27);
  int cx0 = min(max(x0, 0), 27), cx1 = min(max(x1, 0), 27);
  int c0 = cg * 12;
  const short* base = cnn_t + (size_t)b * 784 * 768 + c0 * 8;
  const short* p00 = base + (size_t)(cy0 * 28 + cx0) * 768;
  const short* p01 = base + (size_t)(cy0 * 28 + cx1) * 768;
  const short* p10 = base + (size_t)(cy1 * 28 + cx0) * 768;
  const short* p11 = base + (size_t)(cy1 * 28 + cx1) * 768;
  short* op = sp + ((size_t)(tap * 96 + c0) * 6272 + b * 784 + yx) * 8;
#pragma unroll 4
  for (int i = 0; i < 12; ++i) {
    v8s a = *(const v8s*)(p00 + i * 8);
    v8s bb = *(const v8s*)(p01 + i * 8);
    v8s c = *(const v8s*)(p10 + i * 8);
    v8s d = *(const v8s*)(p11 + i * 8);
    v8s o;
#pragma unroll
    for (int j = 0; j < 8; j++) {
      float v = w00 * bf2f(a[j]) + w01 * bf2f(bb[j]) + w10 * bf2f(c[j]) + w11 * bf2f(d[j]);
      o[j] = f2bf(v);
    }
    *(v8s*)op = o;
    op += (size_t)6272 * 8;
  }
}

// ---------- launch ----------
extern "C" void kernel_launch(void* const* d_in, const int* in_sizes, int n_in,
                              void* d_out, int out_size, void* d_ws, size_t ws_size,
                              hipStream_t stream) {
  const float* cnn   = (const float*)d_in[0];
  const float* vit   = (const float*)d_in[1];
  const float* w_off = (const float*)d_in[2];
  const float* b_off = (const float*)d_in[3];
  const float* w_def = (const float*)d_in[4];
  const float* b_def = (const float*)d_in[5];
  const float* w1    = (const float*)d_in[6];
  const float* b1    = (const float*)d_in[7];
  const float* w2    = (const float*)d_in[8];
  const float* b2    = (const float*)d_in[9];
  float* out = (float*)d_out;
  char* ws = (char*)d_ws;

  short* wdef_p  = (short*)(ws + 0);          // 10,616,832
  short* w1_p    = (short*)(ws + 10616832);   //  7,077,888
  short* w2_p    = (short*)(ws + 17694720);   //  7,077,888
  short* woff2_p = (short*)(ws + 24772608);   //  1,474,560
  short* v_t     = (short*)(ws + 26247168);   // 12,042,240
  float* offs    = (float*)(ws + 38289408);   //    451,584
  float* part    = (float*)(ws + 38740992);   //  4,816,896 (dead after reduce_off2)
  short* sp      = (short*)(ws + 38740992);   // 86,704,128 (aliases part; dead after deform)
  float* part1   = (float*)(ws + 38740992);   //  6,422,528 (aliases sp; conv1 partials)
  float* part2   = (float*)(ws + 45163520);   //  9,633,792 (conv2 partials)
  short* d_t     = (short*)(ws + 125445120);  //  9,633,792
  short* h_t     = (short*)(ws + 135078912);  //  1,605,632
  short* cnn_t   = (short*)(ws + 136684544);  //  9,633,792
  short* zp      = (short*)(ws + 146318336);  // 256 zero page
  // total 146,318,592 bytes

  dim3 blk(256);
  // fused weight preps + NHWC transposes + zp clear (one launch, 56,617 blocks)
  prep_fused_k<<<56617, blk, 0, stream>>>(w_def, w1, w2, w_off, vit, cnn,
                                          wdef_p, w1_p, w2_p, woff2_p, v_t, cnn_t, zp);

  // offset q-GEMM: q[o*9+tap][n14], split-K x4 -> partials
  gemm_k<0, 64, 64, 2, 192, 3840, 960, 1568, 14, 14, 14, 1, 0>
      <<<dim3(25, 3, 4), blk, 0, stream>>>(woff2_p, v_t, nullptr, part, zp);
  // gather-reduce -> offs[b][18][28][28]
  reduce_off2_k<<<441, blk, 0, stream>>>(part, b_off, offs);

  // bilinear sampling -> sp panels (batch-pinned XCD, 2304 blocks)
  sample_k<<<2304, blk, 0, stream>>>(cnn_t, offs, sp);

  // deformable conv GEMM -> d_t (NHWC bf16), 128x64 tiles, 588 blocks, m-fastest XCD order
  gemm_k<1, 128, 64, 2, 768, 768, 6912, 6272, 28, 28, 28, 1, 0>
      <<<dim3(98, 6, 1), blk, 0, stream>>>(wdef_p, sp, b_def, d_t, zp);

  // conv1 stride 2, split-K x2 (XCD m-fastest) -> fp32 partials -> reduce(+bias+relu) -> h_t
  gemm_k<2, 64, 64, 2, 512, 768, 3456, 1568, 28, 28, 14, 2, 1>
      <<<dim3(25, 8, 2), blk, 0, stream>>>(w1_p, d_t, b1, part1, zp);
  reduce_c1_k<<<784, blk, 0, stream>>>(part1, b1, h_t);

  // conv2 split-K x2 -> fp32 partials -> reduce(+bias) -> out
  gemm_k<3, 64, 64, 2, 768, 512, 2304, 1568, 14, 14, 14, 1, 1>
      <<<dim3(25, 12, 2), blk, 0, stream>>>(w2_p, h_t, b2, part2, zp);
  reduce_c2_k<<<1176, blk, 0, stream>>>(part2, b2, out);
}

// Round 14
// 268.027 us; speedup vs baseline: 1.2836x; 1.0370x over previous
//
#include <hip/hip_runtime.h>
#include <hip/hip_bf16.h>
#include <stdint.h>

typedef __attribute__((ext_vector_type(8))) short v8s;
typedef __attribute__((ext_vector_type(4))) short v4s;
typedef __attribute__((ext_vector_type(4))) float v4f;

__device__ __forceinline__ short f2bf(float f) {
  union { float f; uint32_t u; } v; v.f = f;
  uint32_t u = v.u;
  uint32_t r = (u + 0x7fffu + ((u >> 16) & 1u)) >> 16;
  return (short)r;
}
__device__ __forceinline__ float bf2f(short s) {
  union { uint32_t u; float f; } v;
  v.u = ((uint32_t)(uint16_t)s) << 16;
  return v.f;
}
__device__ __forceinline__ void gload16(const void* g, void* l) {
  __builtin_amdgcn_global_load_lds(
      (const __attribute__((address_space(1))) void*)g,
      (__attribute__((address_space(3))) void*)l, 16, 0, 0);
}

// ---------- fused prep: 4 weight panels + 2 NHWC transposes + zp clear, one launch ----------
__global__ __launch_bounds__(256) void prep_fused_k(
    const float* __restrict__ wdef, const float* __restrict__ w1,
    const float* __restrict__ w2, const float* __restrict__ woff,
    const float* __restrict__ vit, const float* __restrict__ cnn,
    short* __restrict__ wdef_p, short* __restrict__ w1_p,
    short* __restrict__ w2_p, short* __restrict__ woff2_p,
    short* __restrict__ v_t, short* __restrict__ cnn_t,
    short* __restrict__ zp) {
  __shared__ float lds[32][65];
  int blk = blockIdx.x;
  int t = threadIdx.x;
  if (blk < 20736) {                       // wdef panels [864][768][8]
    int i = blk * 256 + t;
    int e = i & 7, o = (i >> 3) % 768, p = i / (8 * 768);
    int k = p * 8 + e, tap = k / 768, c = k % 768;
    wdef_p[i] = f2bf(wdef[((size_t)o * 768 + c) * 9 + tap]);
    return;
  }
  blk -= 20736;
  if (blk < 13824) {                       // w1 panels [864][512][8]
    int i = blk * 256 + t;
    int e = i & 7, o = (i >> 3) % 512, p = i / (8 * 512);
    int k = p * 8 + e, tap = k / 768, c = k % 768;
    w1_p[i] = f2bf(w1[((size_t)o * 768 + c) * 9 + tap]);
    return;
  }
  blk -= 13824;
  if (blk < 13824) {                       // w2 panels [576][768][8]
    int i = blk * 256 + t;
    int e = i & 7, o = (i >> 3) % 768, p = i / (8 * 768);
    int k = p * 8 + e, tap = k / 512, c = k % 512;
    w2_p[i] = f2bf(w2[((size_t)o * 512 + c) * 9 + tap]);
    return;
  }
  blk -= 13824;
  if (blk < 2880) {                        // woff2 panels [480][192][8]
    int i = blk * 256 + t;
    int e = i & 7, m = (i >> 3) % 192, kp = i / 1536;
    int c = kp * 8 + e, o = m / 9, tap = m % 9;
    woff2_p[i] = (m < 162) ? f2bf(woff[((size_t)o * 3840 + c) * 9 + tap]) : (short)0;
    return;
  }
  blk -= 2880;
  if (blk >= 3000 + 2352) {                // zp clear (256 bytes)
    if (t < 128) zp[t] = 0;
    return;
  }
  const float* in; short* out; int C, P, bx, by;
  if (blk < 3000) { in = vit; out = v_t; C = 3840; P = 196; bx = blk % 25; by = blk / 25; }
  else { blk -= 3000; in = cnn; out = cnn_t; C = 768; P = 784; bx = blk % 98; by = blk / 98; }
  int n0 = bx * 64, c0 = by * 32;
#pragma unroll
  for (int e = 0; e < 8; e++) {
    int id = e * 256 + t;
    int cl = id >> 6, nl = id & 63;
    int n = n0 + nl;
    if (n < 8 * P) {
      int b = n / P, p = n % P;
      lds[cl][nl] = in[((size_t)b * C + c0 + cl) * P + p];
    }
  }
  __syncthreads();
  int nl = t >> 2, cs = (t & 3) * 8;
  int n = n0 + nl;
  if (n < 8 * P) {
    v8s v;
#pragma unroll
    for (int i = 0; i < 8; i++) v[i] = f2bf(lds[cs + i][nl]);
    *(v8s*)(out + (size_t)n * C + c0 + cs) = v;
  }
}

// ---------- GEMM: BK=64, double-buffered prefetch, gload_lds staging (r6/r11 proven) ----------
// MODE 0: offset q-GEMM (B = v_t direct, dst fp32 partials, split-K)
// MODE 1: deform GEMM  (B = sp panels, dst NHWC bf16 +bias), 128x64, 588 blocks
// MODE 2: conv1 s2 (B = im2col(d_t); PART: fp32 NHWC partials), XCD m-fastest swizzle
// MODE 3: conv2 (B = im2col(h_t); PART: fp32 [z][768][1568] partials), XCD m-fastest swizzle
template<int MODE, int BM, int BN, int WGM, int AO, int CIN, int KSPLIT,
         int NVALID, int IH, int IW, int OW, int STRIDE, int PART>
__global__ __launch_bounds__(256) void gemm_k(const short* __restrict__ Ap,
                                              const short* __restrict__ Bp,
                                              const float* __restrict__ bias,
                                              void* __restrict__ dst,
                                              const short* __restrict__ zp) {
  constexpr int WGN = 4 / WGM;
  constexpr int WM = BM / WGM, WN = BN / WGN;
  constexpr int MF = WM / 16, NF = WN / 16;
  constexpr int CHA = BM * 8, CHT = (BM + BN) * 8;
  constexpr int NT = KSPLIT / 64;

  __shared__ __align__(16) short SM[2][CHT * 8];

  const int tid = threadIdx.x;
  const int lane = tid & 63, wid = tid >> 6;
  const int wm = wid / WGN, wn = wid % WGN;
  int bx = blockIdx.x, by = blockIdx.y;
  if constexpr (MODE == 1) {
    // bijective XCD swizzle, nwg = 588 = 8*73 + 4; m-fastest within XCD chunk
    int bid = by * 98 + bx;
    int xcd = bid & 7, idx = bid >> 3;
    constexpr int q = 73, r = 4;
    int wg = (xcd < r ? xcd * (q + 1) : r * (q + 1) + (xcd - r) * q) + idx;
    by = wg % 6; bx = wg / 6;
  }
  if constexpr (MODE == 2) {
    // 200 blocks per z-slice = 8*25 exact; m-fastest (8 m-tiles share d_t window)
    int bid = by * 25 + bx;
    int swz = (bid & 7) * 25 + (bid >> 3);
    by = swz % 8; bx = swz / 8;
  }
  if constexpr (MODE == 3) {
    // 300 blocks per z-slice = 8*37 + 4; bijective, m-fastest (12 m-tiles share h_t)
    int bid = by * 25 + bx;
    int xcd = bid & 7, idx = bid >> 3;
    constexpr int q = 37, r = 4;
    int wg = (xcd < r ? xcd * (q + 1) : r * (q + 1) + (xcd - r) * q) + idx;
    by = wg % 12; bx = wg / 12;
  }
  const int n0 = bx * BN, m0 = by * BM;
  const int ts = blockIdx.z;
  const int kbeg = ts * KSPLIT;
  const int lrow = lane & 15, lkg = lane >> 4;

  v4f acc[MF][NF];
#pragma unroll
  for (int i = 0; i < MF; i++)
#pragma unroll
    for (int j = 0; j < NF; j++) acc[i][j] = (v4f){0.f, 0.f, 0.f, 0.f};

  auto stage = [&](int k, int buf) {
#pragma unroll
    for (int it = 0; it < CHT / 256; it++) {
      int ch = it * 256 + tid;
      const short* src;
      if (ch < CHA) {
        int kg = ch / BM, row = ch % BM;
        src = Ap + ((size_t)((k >> 3) + kg) * AO + m0 + row) * 8;
      } else {
        int bch = ch - CHA;
        int kg = bch / BN, col = bch % BN;
        int gk = k + kg * 8;
        int n = n0 + col;
        if constexpr (MODE == 0) {
          src = (n < NVALID) ? Bp + ((size_t)n * 3840 + gk) : zp;
        } else if constexpr (MODE == 1) {
          src = Bp + ((size_t)(gk >> 3) * 6272 + n) * 8;
        } else {
          int tap = gk / CIN, cc = gk % CIN;
          int b = n / (OW * OW), rem = n % (OW * OW);
          int oy = rem / OW, ox = rem % OW;
          int py = oy * STRIDE + tap / 3 - 1, px = ox * STRIDE + tap % 3 - 1;
          src = (n < NVALID && py >= 0 && py < IH && px >= 0 && px < IW)
                  ? Bp + ((size_t)((b * IH + py) * IW + px) * CIN + cc)
                  : zp;
        }
      }
      gload16(src, &SM[buf][(size_t)(it * 256 + (tid & ~63)) * 8]);
    }
  };

  stage(kbeg, 0);
  __syncthreads();
  int buf = 0;
  for (int t = 0; t < NT; ++t) {
    if (t + 1 < NT) stage(kbeg + (t + 1) * 64, buf ^ 1);
    v8s af[2][MF], bfv[2][NF];
#pragma unroll
    for (int s = 0; s < 2; s++) {
#pragma unroll
      for (int mf = 0; mf < MF; mf++)
        af[s][mf] = *(const v8s*)(&SM[buf][(size_t)((s * 4 + lkg) * BM + wm * WM + mf * 16 + lrow) * 8]);
#pragma unroll
      for (int nf = 0; nf < NF; nf++)
        bfv[s][nf] = *(const v8s*)(&SM[buf][(size_t)(CHA + (s * 4 + lkg) * BN + wn * WN + nf * 16 + lrow) * 8]);
    }
#pragma unroll
    for (int s = 0; s < 2; s++)
#pragma unroll
      for (int mf = 0; mf < MF; mf++)
#pragma unroll
        for (int nf = 0; nf < NF; nf++)
          acc[mf][nf] = __builtin_amdgcn_mfma_f32_16x16x32_bf16(af[s][mf], bfv[s][nf], acc[mf][nf], 0, 0, 0);
    __syncthreads();
    buf ^= 1;
  }

#pragma unroll
  for (int mf = 0; mf < MF; mf++) {
    int gm = m0 + wm * WM + mf * 16 + lkg * 4;
#pragma unroll
    for (int nf = 0; nf < NF; nf++) {
      int gn = n0 + wn * WN + nf * 16 + lrow;
      v4f a4 = acc[mf][nf];
      if constexpr (MODE == 0) {
        float* part = (float*)dst;
        if (gn < NVALID) {
#pragma unroll
          for (int r = 0; r < 4; r++)
            part[((size_t)ts * AO + gm + r) * 1568 + gn] = a4[r];
        }
      } else if constexpr (MODE == 1) {
        short* dt = (short*)dst;
        v4s v;
#pragma unroll
        for (int r = 0; r < 4; r++) v[r] = f2bf(a4[r] + bias[gm + r]);
        *(v4s*)(dt + (size_t)gn * 768 + gm) = v;
      } else if constexpr (MODE == 2) {
        if (gn < NVALID) {
          float* pd = (float*)dst;
          *(v4f*)(pd + ((size_t)ts * 1568 + gn) * 512 + gm) = a4;
        }
      } else {
        if (gn < NVALID) {
          float* pd = (float*)dst;
#pragma unroll
          for (int r = 0; r < 4; r++)
            pd[((size_t)(ts * 768) + gm + r) * 1568 + gn] = a4[r];
        }
      }
    }
  }
}

// ---------- offset gather-reduce: offs[b][18][28][28] from q partials ----------
__global__ __launch_bounds__(256) void reduce_off2_k(const float* __restrict__ part,
                                                     const float* __restrict__ boff,
                                                     float* __restrict__ offs) {
  int i = blockIdx.x * 256 + threadIdx.x;
  if (i >= 8 * 18 * 784) return;
  int b = i / (18 * 784), r = i % (18 * 784);
  int o = r / 784, yx = r % 784;
  int y = yx / 28, x = yx % 28;
  float s = boff[o];
#pragma unroll
  for (int tap = 0; tap < 9; tap++) {
    int py = y + tap / 3 - 1, px = x + tap % 3 - 1;
    if (py >= 0 && py < 28 && px >= 0 && px < 28) {
      int n = b * 196 + (py >> 1) * 14 + (px >> 1);
      int m = o * 9 + tap;
#pragma unroll
      for (int z = 0; z < 4; z++)
        s += part[((size_t)z * 192 + m) * 1568 + n];
    }
  }
  offs[i] = s;
}

// ---------- conv1 split-K(3) reduce: partials [3][1568][512] -> h_t NHWC bf16 (+bias, relu) ----------
__global__ __launch_bounds__(256) void reduce_c1_k(const float* __restrict__ part,
                                                   const float* __restrict__ b1,
                                                   short* __restrict__ h_t) {
  int i = blockIdx.x * 256 + threadIdx.x;
  if (i >= 1568 * 128) return;
  int n = i >> 7, o4 = (i & 127) * 4;
  v4f s0 = *(const v4f*)(part + ((size_t)n) * 512 + o4);
  v4f s1 = *(const v4f*)(part + ((size_t)(1568 + n)) * 512 + o4);
  v4f s2 = *(const v4f*)(part + ((size_t)(3136 + n)) * 512 + o4);
  v4f bb = *(const v4f*)(b1 + o4);
  v4s v;
#pragma unroll
  for (int r = 0; r < 4; r++) v[r] = f2bf(fmaxf(s0[r] + s1[r] + s2[r] + bb[r], 0.f));
  *(v4s*)(h_t + (size_t)n * 512 + o4) = v;
}

// ---------- conv2 split-K(3) reduce: partials [3][768][1568] -> out fp32 NCHW (+bias) ----------
__global__ __launch_bounds__(256) void reduce_c2_k(const float* __restrict__ part,
                                                   const float* __restrict__ b2,
                                                   float* __restrict__ out) {
  int i = blockIdx.x * 256 + threadIdx.x;
  if (i >= 768 * 392) return;
  int m = i / 392, n4 = (i % 392) * 4;
  v4f s0 = *(const v4f*)(part + (size_t)m * 1568 + n4);
  v4f s1 = *(const v4f*)(part + (size_t)(768 + m) * 1568 + n4);
  v4f s2 = *(const v4f*)(part + (size_t)(1536 + m) * 1568 + n4);
  float bv = b2[m];
  int b = n4 / 196, p = n4 % 196;
  v4f o;
#pragma unroll
  for (int r = 0; r < 4; r++) o[r] = s0[r] + s1[r] + s2[r] + bv;
  *(v4f*)(out + ((size_t)(b * 768 + m)) * 196 + p) = o;
}

// ---------- bilinear sampling: batch-pinned XCD + full TLP (r11 proven) ----------
__global__ __launch_bounds__(256) void sample_k(const short* __restrict__ cnn_t,
                                                const float* __restrict__ offs,
                                                short* __restrict__ sp) {
  int bid = blockIdx.x;
  int b = bid & 7;
  int r = bid >> 3;
  int tap = r >> 5;
  int rr = r & 31;
  int cg = rr >> 2, pg = rr & 3;
  int t = threadIdx.x;
  if (t >= 196) return;
  int yx = pg * 196 + t;
  int y = yx / 28, x = yx % 28;
  float dy = offs[((size_t)b * 18 + tap * 2 + 0) * 784 + yx];
  float dx = offs[((size_t)b * 18 + tap * 2 + 1) * 784 + yx];
  float py = (float)(y + tap / 3 - 1) + dy;
  float px = (float)(x + tap % 3 - 1) + dx;
  float fy = floorf(py), fx = floorf(px);
  float ly = py - fy, lx = px - fx;
  int y0 = (int)fy, x0 = (int)fx;
  int y1 = y0 + 1, x1 = x0 + 1;
  float vy0 = (y0 >= 0 && y0 < 28) ? 1.f : 0.f;
  float vy1 = (y1 >= 0 && y1 < 28) ? 1.f : 0.f;
  float vx0 = (x0 >= 0 && x0 < 28) ? 1.f : 0.f;
  float vx1 = (x1 >= 0 && x1 < 28) ? 1.f : 0.f;
  float w00 = (1.f - ly) * (1.f - lx) * vy0 * vx0;
  float w01 = (1.f - ly) * lx * vy0 * vx1;
  float w10 = ly * (1.f - lx) * vy1 * vx0;
  float w11 = ly * lx * vy1 * vx1;
  int cy0 = min(max(y0, 0), 27), cy1 = min(max(y1, 0), 27);
  int cx0 = min(max(x0, 0), 27), cx1 = min(max(x1, 0), 27);
  int c0 = cg * 12;
  const short* base = cnn_t + (size_t)b * 784 * 768 + c0 * 8;
  const short* p00 = base + (size_t)(cy0 * 28 + cx0) * 768;
  const short* p01 = base + (size_t)(cy0 * 28 + cx1) * 768;
  const short* p10 = base + (size_t)(cy1 * 28 + cx0) * 768;
  const short* p11 = base + (size_t)(cy1 * 28 + cx1) * 768;
  short* op = sp + ((size_t)(tap * 96 + c0) * 6272 + b * 784 + yx) * 8;
#pragma unroll 4
  for (int i = 0; i < 12; ++i) {
    v8s a = *(const v8s*)(p00 + i * 8);
    v8s bb = *(const v8s*)(p01 + i * 8);
    v8s c = *(const v8s*)(p10 + i * 8);
    v8s d = *(const v8s*)(p11 + i * 8);
    v8s o;
#pragma unroll
    for (int j = 0; j < 8; j++) {
      float v = w00 * bf2f(a[j]) + w01 * bf2f(bb[j]) + w10 * bf2f(c[j]) + w11 * bf2f(d[j]);
      o[j] = f2bf(v);
    }
    *(v8s*)op = o;
    op += (size_t)6272 * 8;
  }
}

// ---------- launch ----------
extern "C" void kernel_launch(void* const* d_in, const int* in_sizes, int n_in,
                              void* d_out, int out_size, void* d_ws, size_t ws_size,
                              hipStream_t stream) {
  const float* cnn   = (const float*)d_in[0];
  const float* vit   = (const float*)d_in[1];
  const float* w_off = (const float*)d_in[2];
  const float* b_off = (const float*)d_in[3];
  const float* w_def = (const float*)d_in[4];
  const float* b_def = (const float*)d_in[5];
  const float* w1    = (const float*)d_in[6];
  const float* b1    = (const float*)d_in[7];
  const float* w2    = (const float*)d_in[8];
  const float* b2    = (const float*)d_in[9];
  float* out = (float*)d_out;
  char* ws = (char*)d_ws;

  short* wdef_p  = (short*)(ws + 0);          // 10,616,832
  short* w1_p    = (short*)(ws + 10616832);   //  7,077,888
  short* w2_p    = (short*)(ws + 17694720);   //  7,077,888
  short* woff2_p = (short*)(ws + 24772608);   //  1,474,560
  short* v_t     = (short*)(ws + 26247168);   // 12,042,240
  float* offs    = (float*)(ws + 38289408);   //    451,584
  float* part    = (float*)(ws + 38740992);   //  4,816,896 (dead after reduce_off2)
  short* sp      = (short*)(ws + 38740992);   // 86,704,128 (aliases part; dead after deform)
  float* part1   = (float*)(ws + 38740992);   //  9,633,792 (aliases sp; conv1 partials, z=3)
  float* part2   = (float*)(ws + 48374784);   // 14,450,688 (conv2 partials, z=3)
  short* d_t     = (short*)(ws + 125445120);  //  9,633,792
  short* h_t     = (short*)(ws + 135078912);  //  1,605,632
  short* cnn_t   = (short*)(ws + 136684544);  //  9,633,792
  short* zp      = (short*)(ws + 146318336);  // 256 zero page
  // total 146,318,592 bytes

  dim3 blk(256);
  // fused weight preps + NHWC transposes + zp clear (one launch, 56,617 blocks)
  prep_fused_k<<<56617, blk, 0, stream>>>(w_def, w1, w2, w_off, vit, cnn,
                                          wdef_p, w1_p, w2_p, woff2_p, v_t, cnn_t, zp);

  // offset q-GEMM: q[o*9+tap][n14], split-K x4 -> partials
  gemm_k<0, 64, 64, 2, 192, 3840, 960, 1568, 14, 14, 14, 1, 0>
      <<<dim3(25, 3, 4), blk, 0, stream>>>(woff2_p, v_t, nullptr, part, zp);
  // gather-reduce -> offs[b][18][28][28]
  reduce_off2_k<<<441, blk, 0, stream>>>(part, b_off, offs);

  // bilinear sampling -> sp panels (batch-pinned XCD, 2304 blocks)
  sample_k<<<2304, blk, 0, stream>>>(cnn_t, offs, sp);

  // deformable conv GEMM -> d_t (NHWC bf16), 128x64 tiles, 588 blocks, m-fastest XCD order
  gemm_k<1, 128, 64, 2, 768, 768, 6912, 6272, 28, 28, 28, 1, 0>
      <<<dim3(98, 6, 1), blk, 0, stream>>>(wdef_p, sp, b_def, d_t, zp);

  // conv1 stride 2, split-K x3 (XCD m-fastest) -> fp32 partials -> reduce(+bias+relu) -> h_t
  gemm_k<2, 64, 64, 2, 512, 768, 2304, 1568, 28, 28, 14, 2, 1>
      <<<dim3(25, 8, 3), blk, 0, stream>>>(w1_p, d_t, b1, part1, zp);
  reduce_c1_k<<<784, blk, 0, stream>>>(part1, b1, h_t);

  // conv2 split-K x3 (XCD m-fastest) -> fp32 partials -> reduce(+bias) -> out
  gemm_k<3, 64, 64, 2, 768, 512, 1536, 1568, 14, 14, 14, 1, 1>
      <<<dim3(25, 12, 3), blk, 0, stream>>>(w2_p, h_t, b2, part2, zp);
  reduce_c2_k<<<1176, blk, 0, stream>>>(part2, b2, out);
}

// Round 15
// 266.801 us; speedup vs baseline: 1.2895x; 1.0046x over previous
//
#include <hip/hip_runtime.h>
#include <hip/hip_bf16.h>
#include <stdint.h>

typedef __attribute__((ext_vector_type(8))) short v8s;
typedef __attribute__((ext_vector_type(4))) short v4s;
typedef __attribute__((ext_vector_type(4))) float v4f;

__device__ __forceinline__ short f2bf(float f) {
  union { float f; uint32_t u; } v; v.f = f;
  uint32_t u = v.u;
  uint32_t r = (u + 0x7fffu + ((u >> 16) & 1u)) >> 16;
  return (short)r;
}
__device__ __forceinline__ float bf2f(short s) {
  union { uint32_t u; float f; } v;
  v.u = ((uint32_t)(uint16_t)s) << 16;
  return v.f;
}
__device__ __forceinline__ void gload16(const void* g, void* l) {
  __builtin_amdgcn_global_load_lds(
      (const __attribute__((address_space(1))) void*)g,
      (__attribute__((address_space(3))) void*)l, 16, 0, 0);
}

// ---------- fused prep: 4 weight panels + 2 NHWC transposes + zp clear, one launch ----------
__global__ __launch_bounds__(256) void prep_fused_k(
    const float* __restrict__ wdef, const float* __restrict__ w1,
    const float* __restrict__ w2, const float* __restrict__ woff,
    const float* __restrict__ vit, const float* __restrict__ cnn,
    short* __restrict__ wdef_p, short* __restrict__ w1_p,
    short* __restrict__ w2_p, short* __restrict__ woff2_p,
    short* __restrict__ v_t, short* __restrict__ cnn_t,
    short* __restrict__ zp) {
  __shared__ float lds[32][65];
  int blk = blockIdx.x;
  int t = threadIdx.x;
  if (blk < 20736) {                       // wdef panels [864][768][8]
    int i = blk * 256 + t;
    int e = i & 7, o = (i >> 3) % 768, p = i / (8 * 768);
    int k = p * 8 + e, tap = k / 768, c = k % 768;
    wdef_p[i] = f2bf(wdef[((size_t)o * 768 + c) * 9 + tap]);
    return;
  }
  blk -= 20736;
  if (blk < 13824) {                       // w1 panels [864][512][8]
    int i = blk * 256 + t;
    int e = i & 7, o = (i >> 3) % 512, p = i / (8 * 512);
    int k = p * 8 + e, tap = k / 768, c = k % 768;
    w1_p[i] = f2bf(w1[((size_t)o * 768 + c) * 9 + tap]);
    return;
  }
  blk -= 13824;
  if (blk < 13824) {                       // w2 panels [576][768][8]
    int i = blk * 256 + t;
    int e = i & 7, o = (i >> 3) % 768, p = i / (8 * 768);
    int k = p * 8 + e, tap = k / 512, c = k % 512;
    w2_p[i] = f2bf(w2[((size_t)o * 512 + c) * 9 + tap]);
    return;
  }
  blk -= 13824;
  if (blk < 2880) {                        // woff2 panels [480][192][8]
    int i = blk * 256 + t;
    int e = i & 7, m = (i >> 3) % 192, kp = i / 1536;
    int c = kp * 8 + e, o = m / 9, tap = m % 9;
    woff2_p[i] = (m < 162) ? f2bf(woff[((size_t)o * 3840 + c) * 9 + tap]) : (short)0;
    return;
  }
  blk -= 2880;
  if (blk >= 3000 + 2352) {                // zp clear (256 bytes)
    if (t < 128) zp[t] = 0;
    return;
  }
  const float* in; short* out; int C, P, bx, by;
  if (blk < 3000) { in = vit; out = v_t; C = 3840; P = 196; bx = blk % 25; by = blk / 25; }
  else { blk -= 3000; in = cnn; out = cnn_t; C = 768; P = 784; bx = blk % 98; by = blk / 98; }
  int n0 = bx * 64, c0 = by * 32;
#pragma unroll
  for (int e = 0; e < 8; e++) {
    int id = e * 256 + t;
    int cl = id >> 6, nl = id & 63;
    int n = n0 + nl;
    if (n < 8 * P) {
      int b = n / P, p = n % P;
      lds[cl][nl] = in[((size_t)b * C + c0 + cl) * P + p];
    }
  }
  __syncthreads();
  int nl = t >> 2, cs = (t & 3) * 8;
  int n = n0 + nl;
  if (n < 8 * P) {
    v8s v;
#pragma unroll
    for (int i = 0; i < 8; i++) v[i] = f2bf(lds[cs + i][nl]);
    *(v8s*)(out + (size_t)n * C + c0 + cs) = v;
  }
}

// ---------- GEMM: BK=64, double-buffered prefetch, gload_lds staging (r6/r11 proven) ----------
// MODE 0: offset q-GEMM (B = v_t direct, dst fp32 partials, split-K)
// MODE 1: deform GEMM  (B = sp panels, dst NHWC bf16 +bias), 128x64, 588 blocks
// MODE 2: conv1 s2 (B = im2col(d_t); PART fp32 NHWC partials), XCD m-fastest swizzle
// MODE 3: conv2 (B = im2col(h_t); PART fp32 [z][768][1568] partials), XCD m-fastest swizzle
template<int MODE, int BM, int BN, int WGM, int AO, int CIN, int KSPLIT,
         int NVALID, int IH, int IW, int OW, int STRIDE, int PART>
__global__ __launch_bounds__(256) void gemm_k(const short* __restrict__ Ap,
                                              const short* __restrict__ Bp,
                                              const float* __restrict__ bias,
                                              void* __restrict__ dst,
                                              const short* __restrict__ zp) {
  constexpr int WGN = 4 / WGM;
  constexpr int WM = BM / WGM, WN = BN / WGN;
  constexpr int MF = WM / 16, NF = WN / 16;
  constexpr int CHA = BM * 8, CHT = (BM + BN) * 8;
  constexpr int NT = KSPLIT / 64;

  __shared__ __align__(16) short SM[2][CHT * 8];

  const int tid = threadIdx.x;
  const int lane = tid & 63, wid = tid >> 6;
  const int wm = wid / WGN, wn = wid % WGN;
  int bx = blockIdx.x, by = blockIdx.y;
  if constexpr (MODE == 1) {
    // bijective XCD swizzle, nwg = 588 = 8*73 + 4; m-fastest within XCD chunk
    int bid = by * 98 + bx;
    int xcd = bid & 7, idx = bid >> 3;
    constexpr int q = 73, r = 4;
    int wg = (xcd < r ? xcd * (q + 1) : r * (q + 1) + (xcd - r) * q) + idx;
    by = wg % 6; bx = wg / 6;
  }
  if constexpr (MODE == 2) {
    // 200 blocks per z-slice = 8*25 exact; m-fastest (8 m-tiles share d_t window)
    int bid = by * 25 + bx;
    int swz = (bid & 7) * 25 + (bid >> 3);
    by = swz % 8; bx = swz / 8;
  }
  if constexpr (MODE == 3) {
    // 300 blocks per z-slice = 8*37 + 4; bijective, m-fastest (12 m-tiles share h_t)
    int bid = by * 25 + bx;
    int xcd = bid & 7, idx = bid >> 3;
    constexpr int q = 37, r = 4;
    int wg = (xcd < r ? xcd * (q + 1) : r * (q + 1) + (xcd - r) * q) + idx;
    by = wg % 12; bx = wg / 12;
  }
  const int n0 = bx * BN, m0 = by * BM;
  const int ts = blockIdx.z;
  const int kbeg = ts * KSPLIT;
  const int lrow = lane & 15, lkg = lane >> 4;

  v4f acc[MF][NF];
#pragma unroll
  for (int i = 0; i < MF; i++)
#pragma unroll
    for (int j = 0; j < NF; j++) acc[i][j] = (v4f){0.f, 0.f, 0.f, 0.f};

  auto stage = [&](int k, int buf) {
#pragma unroll
    for (int it = 0; it < CHT / 256; it++) {
      int ch = it * 256 + tid;
      const short* src;
      if (ch < CHA) {
        int kg = ch / BM, row = ch % BM;
        src = Ap + ((size_t)((k >> 3) + kg) * AO + m0 + row) * 8;
      } else {
        int bch = ch - CHA;
        int kg = bch / BN, col = bch % BN;
        int gk = k + kg * 8;
        int n = n0 + col;
        if constexpr (MODE == 0) {
          src = (n < NVALID) ? Bp + ((size_t)n * 3840 + gk) : zp;
        } else if constexpr (MODE == 1) {
          src = Bp + ((size_t)(gk >> 3) * 6272 + n) * 8;
        } else {
          int tap = gk / CIN, cc = gk % CIN;
          int b = n / (OW * OW), rem = n % (OW * OW);
          int oy = rem / OW, ox = rem % OW;
          int py = oy * STRIDE + tap / 3 - 1, px = ox * STRIDE + tap % 3 - 1;
          src = (n < NVALID && py >= 0 && py < IH && px >= 0 && px < IW)
                  ? Bp + ((size_t)((b * IH + py) * IW + px) * CIN + cc)
                  : zp;
        }
      }
      gload16(src, &SM[buf][(size_t)(it * 256 + (tid & ~63)) * 8]);
    }
  };

  stage(kbeg, 0);
  __syncthreads();
  int buf = 0;
  for (int t = 0; t < NT; ++t) {
    if (t + 1 < NT) stage(kbeg + (t + 1) * 64, buf ^ 1);
    v8s af[2][MF], bfv[2][NF];
#pragma unroll
    for (int s = 0; s < 2; s++) {
#pragma unroll
      for (int mf = 0; mf < MF; mf++)
        af[s][mf] = *(const v8s*)(&SM[buf][(size_t)((s * 4 + lkg) * BM + wm * WM + mf * 16 + lrow) * 8]);
#pragma unroll
      for (int nf = 0; nf < NF; nf++)
        bfv[s][nf] = *(const v8s*)(&SM[buf][(size_t)(CHA + (s * 4 + lkg) * BN + wn * WN + nf * 16 + lrow) * 8]);
    }
#pragma unroll
    for (int s = 0; s < 2; s++)
#pragma unroll
      for (int mf = 0; mf < MF; mf++)
#pragma unroll
        for (int nf = 0; nf < NF; nf++)
          acc[mf][nf] = __builtin_amdgcn_mfma_f32_16x16x32_bf16(af[s][mf], bfv[s][nf], acc[mf][nf], 0, 0, 0);
    __syncthreads();
    buf ^= 1;
  }

#pragma unroll
  for (int mf = 0; mf < MF; mf++) {
    int gm = m0 + wm * WM + mf * 16 + lkg * 4;
#pragma unroll
    for (int nf = 0; nf < NF; nf++) {
      int gn = n0 + wn * WN + nf * 16 + lrow;
      v4f a4 = acc[mf][nf];
      if constexpr (MODE == 0) {
        float* part = (float*)dst;
        if (gn < NVALID) {
#pragma unroll
          for (int r = 0; r < 4; r++)
            part[((size_t)ts * AO + gm + r) * 1568 + gn] = a4[r];
        }
      } else if constexpr (MODE == 1) {
        short* dt = (short*)dst;
        v4s v;
#pragma unroll
        for (int r = 0; r < 4; r++) v[r] = f2bf(a4[r] + bias[gm + r]);
        *(v4s*)(dt + (size_t)gn * 768 + gm) = v;
      } else if constexpr (MODE == 2) {
        if (gn < NVALID) {
          float* pd = (float*)dst;
          *(v4f*)(pd + ((size_t)ts * 1568 + gn) * 512 + gm) = a4;
        }
      } else {
        if (gn < NVALID) {
          float* pd = (float*)dst;
#pragma unroll
          for (int r = 0; r < 4; r++)
            pd[((size_t)(ts * 768) + gm + r) * 1568 + gn] = a4[r];
        }
      }
    }
  }
}

// ---------- offset gather-reduce: offs[b][18][28][28] from q partials ----------
__global__ __launch_bounds__(256) void reduce_off2_k(const float* __restrict__ part,
                                                     const float* __restrict__ boff,
                                                     float* __restrict__ offs) {
  int i = blockIdx.x * 256 + threadIdx.x;
  if (i >= 8 * 18 * 784) return;
  int b = i / (18 * 784), r = i % (18 * 784);
  int o = r / 784, yx = r % 784;
  int y = yx / 28, x = yx % 28;
  float s = boff[o];
#pragma unroll
  for (int tap = 0; tap < 9; tap++) {
    int py = y + tap / 3 - 1, px = x + tap % 3 - 1;
    if (py >= 0 && py < 28 && px >= 0 && px < 28) {
      int n = b * 196 + (py >> 1) * 14 + (px >> 1);
      int m = o * 9 + tap;
#pragma unroll
      for (int z = 0; z < 4; z++)
        s += part[((size_t)z * 192 + m) * 1568 + n];
    }
  }
  offs[i] = s;
}

// ---------- conv1 split-K(3) reduce: partials [3][1568][512] -> h_t NHWC bf16 (+bias, relu) ----------
__global__ __launch_bounds__(256) void reduce_c1_k(const float* __restrict__ part,
                                                   const float* __restrict__ b1,
                                                   short* __restrict__ h_t) {
  int i = blockIdx.x * 256 + threadIdx.x;
  if (i >= 1568 * 128) return;
  int n = i >> 7, o4 = (i & 127) * 4;
  v4f s0 = *(const v4f*)(part + ((size_t)n) * 512 + o4);
  v4f s1 = *(const v4f*)(part + ((size_t)(1568 + n)) * 512 + o4);
  v4f s2 = *(const v4f*)(part + ((size_t)(3136 + n)) * 512 + o4);
  v4f bb = *(const v4f*)(b1 + o4);
  v4s v;
#pragma unroll
  for (int r = 0; r < 4; r++) v[r] = f2bf(fmaxf(s0[r] + s1[r] + s2[r] + bb[r], 0.f));
  *(v4s*)(h_t + (size_t)n * 512 + o4) = v;
}

// ---------- conv2 split-K(3) reduce: partials [3][768][1568] -> out fp32 NCHW (+bias) ----------
__global__ __launch_bounds__(256) void reduce_c2_k(const float* __restrict__ part,
                                                   const float* __restrict__ b2,
                                                   float* __restrict__ out) {
  int i = blockIdx.x * 256 + threadIdx.x;
  if (i >= 768 * 392) return;
  int m = i / 392, n4 = (i % 392) * 4;
  v4f s0 = *(const v4f*)(part + (size_t)m * 1568 + n4);
  v4f s1 = *(const v4f*)(part + (size_t)(768 + m) * 1568 + n4);
  v4f s2 = *(const v4f*)(part + (size_t)(1536 + m) * 1568 + n4);
  float bv = b2[m];
  int b = n4 / 196, p = n4 % 196;
  v4f o;
#pragma unroll
  for (int r = 0; r < 4; r++) o[r] = s0[r] + s1[r] + s2[r] + bv;
  *(v4f*)(out + ((size_t)(b * 768 + m)) * 196 + p) = o;
}

// ---------- bilinear sampling: batch-pinned XCD, full-thread blocks ----------
// grid 1800 = 8 b x 9 tap x 25 j; b = bid&7 (XCD-pinned, cnn_t slice L2-resident).
// Per (b,tap): 6272 items = 8 cg x 784 yx covered by 25 x 256 threads (98% full);
// each thread owns (yx, cg) and walks 12 sequential channel-slices.
__global__ __launch_bounds__(256) void sample_k(const short* __restrict__ cnn_t,
                                                const float* __restrict__ offs,
                                                short* __restrict__ sp) {
  int bid = blockIdx.x;
  int b = bid & 7;
  int r = bid >> 3;            // tap*25 + j
  int tap = r / 25, j = r % 25;
  int item = j * 256 + threadIdx.x;
  if (item >= 6272) return;
  int cg = item / 784;
  int yx = item - cg * 784;
  int y = yx / 28, x = yx % 28;
  float dy = offs[((size_t)b * 18 + tap * 2 + 0) * 784 + yx];
  float dx = offs[((size_t)b * 18 + tap * 2 + 1) * 784 + yx];
  float py = (float)(y + tap / 3 - 1) + dy;
  float px = (float)(x + tap % 3 - 1) + dx;
  float fy = floorf(py), fx = floorf(px);
  float ly = py - fy, lx = px - fx;
  int y0 = (int)fy, x0 = (int)fx;
  int y1 = y0 + 1, x1 = x0 + 1;
  float vy0 = (y0 >= 0 && y0 < 28) ? 1.f : 0.f;
  float vy1 = (y1 >= 0 && y1 < 28) ? 1.f : 0.f;
  float vx0 = (x0 >= 0 && x0 < 28) ? 1.f : 0.f;
  float vx1 = (x1 >= 0 && x1 < 28) ? 1.f : 0.f;
  float w00 = (1.f - ly) * (1.f - lx) * vy0 * vx0;
  float w01 = (1.f - ly) * lx * vy0 * vx1;
  float w10 = ly * (1.f - lx) * vy1 * vx0;
  float w11 = ly * lx * vy1 * vx1;
  int cy0 = min(max(y0, 0), 27), cy1 = min(max(y1, 0), 27);
  int cx0 = min(max(x0, 0), 27), cx1 = min(max(x1, 0), 27);
  int c0 = cg * 12;
  const short* base = cnn_t + (size_t)b * 784 * 768 + c0 * 8;
  const short* p00 = base + (size_t)(cy0 * 28 + cx0) * 768;
  const short* p01 = base + (size_t)(cy0 * 28 + cx1) * 768;
  const short* p10 = base + (size_t)(cy1 * 28 + cx0) * 768;
  const short* p11 = base + (size_t)(cy1 * 28 + cx1) * 768;
  short* op = sp + ((size_t)(tap * 96 + c0) * 6272 + b * 784 + yx) * 8;
#pragma unroll 4
  for (int i = 0; i < 12; ++i) {
    v8s a = *(const v8s*)(p00 + i * 8);
    v8s bb = *(const v8s*)(p01 + i * 8);
    v8s c = *(const v8s*)(p10 + i * 8);
    v8s d = *(const v8s*)(p11 + i * 8);
    v8s o;
#pragma unroll
    for (int jj = 0; jj < 8; jj++) {
      float v = w00 * bf2f(a[jj]) + w01 * bf2f(bb[jj]) + w10 * bf2f(c[jj]) + w11 * bf2f(d[jj]);
      o[jj] = f2bf(v);
    }
    *(v8s*)op = o;
    op += (size_t)6272 * 8;
  }
}

// ---------- launch ----------
extern "C" void kernel_launch(void* const* d_in, const int* in_sizes, int n_in,
                              void* d_out, int out_size, void* d_ws, size_t ws_size,
                              hipStream_t stream) {
  const float* cnn   = (const float*)d_in[0];
  const float* vit   = (const float*)d_in[1];
  const float* w_off = (const float*)d_in[2];
  const float* b_off = (const float*)d_in[3];
  const float* w_def = (const float*)d_in[4];
  const float* b_def = (const float*)d_in[5];
  const float* w1    = (const float*)d_in[6];
  const float* b1    = (const float*)d_in[7];
  const float* w2    = (const float*)d_in[8];
  const float* b2    = (const float*)d_in[9];
  float* out = (float*)d_out;
  char* ws = (char*)d_ws;

  short* wdef_p  = (short*)(ws + 0);          // 10,616,832
  short* w1_p    = (short*)(ws + 10616832);   //  7,077,888
  short* w2_p    = (short*)(ws + 17694720);   //  7,077,888
  short* woff2_p = (short*)(ws + 24772608);   //  1,474,560
  short* v_t     = (short*)(ws + 26247168);   // 12,042,240
  float* offs    = (float*)(ws + 38289408);   //    451,584
  float* part    = (float*)(ws + 38740992);   //  4,816,896 (dead after reduce_off2)
  short* sp      = (short*)(ws + 38740992);   // 86,704,128 (aliases part; dead after deform)
  float* part1   = (float*)(ws + 38740992);   //  9,633,792 (aliases sp; conv1 partials, z=3)
  float* part2   = (float*)(ws + 48374784);   // 14,450,688 (conv2 partials, z=3)
  short* d_t     = (short*)(ws + 125445120);  //  9,633,792
  short* h_t     = (short*)(ws + 135078912);  //  1,605,632
  short* cnn_t   = (short*)(ws + 136684544);  //  9,633,792
  short* zp      = (short*)(ws + 146318336);  // 256 zero page
  // total 146,318,592 bytes

  dim3 blk(256);
  // fused weight preps + NHWC transposes + zp clear (one launch, 56,617 blocks)
  prep_fused_k<<<56617, blk, 0, stream>>>(w_def, w1, w2, w_off, vit, cnn,
                                          wdef_p, w1_p, w2_p, woff2_p, v_t, cnn_t, zp);

  // offset q-GEMM: q[o*9+tap][n14], split-K x4 -> partials
  gemm_k<0, 64, 64, 2, 192, 3840, 960, 1568, 14, 14, 14, 1, 0>
      <<<dim3(25, 3, 4), blk, 0, stream>>>(woff2_p, v_t, nullptr, part, zp);
  // gather-reduce -> offs[b][18][28][28]
  reduce_off2_k<<<441, blk, 0, stream>>>(part, b_off, offs);

  // bilinear sampling -> sp panels (batch-pinned XCD, 1800 full-thread blocks)
  sample_k<<<1800, blk, 0, stream>>>(cnn_t, offs, sp);

  // deformable conv GEMM -> d_t (NHWC bf16), 128x64 tiles, 588 blocks, m-fastest XCD order
  gemm_k<1, 128, 64, 2, 768, 768, 6912, 6272, 28, 28, 28, 1, 0>
      <<<dim3(98, 6, 1), blk, 0, stream>>>(wdef_p, sp, b_def, d_t, zp);

  // conv1 stride 2, split-K x3 (XCD m-fastest) -> fp32 partials -> reduce(+bias+relu) -> h_t
  gemm_k<2, 64, 64, 2, 512, 768, 2304, 1568, 28, 28, 14, 2, 1>
      <<<dim3(25, 8, 3), blk, 0, stream>>>(w1_p, d_t, b1, part1, zp);
  reduce_c1_k<<<784, blk, 0, stream>>>(part1, b1, h_t);

  // conv2 split-K x3 (XCD m-fastest) -> fp32 partials -> reduce(+bias) -> out
  gemm_k<3, 64, 64, 2, 768, 512, 1536, 1568, 14, 14, 14, 1, 1>
      <<<dim3(25, 12, 3), blk, 0, stream>>>(w2_p, h_t, b2, part2, zp);
  reduce_c2_k<<<1176, blk, 0, stream>>>(part2, b2, out);
}

// Round 16
// 257.446 us; speedup vs baseline: 1.3364x; 1.0363x over previous
//
#include <hip/hip_runtime.h>
#include <hip/hip_bf16.h>
#include <stdint.h>

typedef __attribute__((ext_vector_type(8))) short v8s;
typedef __attribute__((ext_vector_type(4))) short v4s;
typedef __attribute__((ext_vector_type(4))) float v4f;

__device__ __forceinline__ short f2bf(float f) {
  union { float f; uint32_t u; } v; v.f = f;
  uint32_t u = v.u;
  uint32_t r = (u + 0x7fffu + ((u >> 16) & 1u)) >> 16;
  return (short)r;
}
__device__ __forceinline__ float bf2f(short s) {
  union { uint32_t u; float f; } v;
  v.u = ((uint32_t)(uint16_t)s) << 16;
  return v.f;
}
__device__ __forceinline__ void gload16(const void* g, void* l) {
  __builtin_amdgcn_global_load_lds(
      (const __attribute__((address_space(1))) void*)g,
      (__attribute__((address_space(3))) void*)l, 16, 0, 0);
}

// ---------- fused prep: 4 weight panels + 2 transposes + zp clear, one launch ----------
// vit -> v_t K-PANELS [480][1568][8]; cnn -> cnn_t NHWC [6272][768] (sample_k needs NHWC)
__global__ __launch_bounds__(256) void prep_fused_k(
    const float* __restrict__ wdef, const float* __restrict__ w1,
    const float* __restrict__ w2, const float* __restrict__ woff,
    const float* __restrict__ vit, const float* __restrict__ cnn,
    short* __restrict__ wdef_p, short* __restrict__ w1_p,
    short* __restrict__ w2_p, short* __restrict__ woff2_p,
    short* __restrict__ v_t, short* __restrict__ cnn_t,
    short* __restrict__ zp) {
  __shared__ float lds[32][65];
  int blk = blockIdx.x;
  int t = threadIdx.x;
  if (blk < 20736) {                       // wdef panels [864][768][8]
    int i = blk * 256 + t;
    int e = i & 7, o = (i >> 3) % 768, p = i / (8 * 768);
    int k = p * 8 + e, tap = k / 768, c = k % 768;
    wdef_p[i] = f2bf(wdef[((size_t)o * 768 + c) * 9 + tap]);
    return;
  }
  blk -= 20736;
  if (blk < 13824) {                       // w1 panels [864][512][8]
    int i = blk * 256 + t;
    int e = i & 7, o = (i >> 3) % 512, p = i / (8 * 512);
    int k = p * 8 + e, tap = k / 768, c = k % 768;
    w1_p[i] = f2bf(w1[((size_t)o * 768 + c) * 9 + tap]);
    return;
  }
  blk -= 13824;
  if (blk < 13824) {                       // w2 panels [576][768][8]
    int i = blk * 256 + t;
    int e = i & 7, o = (i >> 3) % 768, p = i / (8 * 768);
    int k = p * 8 + e, tap = k / 512, c = k % 512;
    w2_p[i] = f2bf(w2[((size_t)o * 512 + c) * 9 + tap]);
    return;
  }
  blk -= 13824;
  if (blk < 2880) {                        // woff2 panels [480][192][8]
    int i = blk * 256 + t;
    int e = i & 7, m = (i >> 3) % 192, kp = i / 1536;
    int c = kp * 8 + e, o = m / 9, tap = m % 9;
    woff2_p[i] = (m < 162) ? f2bf(woff[((size_t)o * 3840 + c) * 9 + tap]) : (short)0;
    return;
  }
  blk -= 2880;
  if (blk >= 3000 + 2352) {                // zp clear (256 bytes)
    if (t < 128) zp[t] = 0;
    return;
  }
  const float* in; short* out; int C, P, bx, by; bool panel;
  if (blk < 3000) { in = vit; out = v_t; C = 3840; P = 196; bx = blk % 25; by = blk / 25; panel = true; }
  else { blk -= 3000; in = cnn; out = cnn_t; C = 768; P = 784; bx = blk % 98; by = blk / 98; panel = false; }
  int n0 = bx * 64, c0 = by * 32;
#pragma unroll
  for (int e = 0; e < 8; e++) {
    int id = e * 256 + t;
    int cl = id >> 6, nl = id & 63;
    int n = n0 + nl;
    if (n < 8 * P) {
      int b = n / P, p = n % P;
      lds[cl][nl] = in[((size_t)b * C + c0 + cl) * P + p];
    }
  }
  __syncthreads();
  int nl = t >> 2, cs = (t & 3) * 8;
  int n = n0 + nl;
  if (n < 8 * P) {
    v8s v;
#pragma unroll
    for (int i = 0; i < 8; i++) v[i] = f2bf(lds[cs + i][nl]);
    if (panel)
      *(v8s*)(out + ((size_t)((c0 + cs) >> 3) * (8 * P) + n) * 8) = v;
    else
      *(v8s*)(out + (size_t)n * C + c0 + cs) = v;
  }
}

// ---------- GEMM: BK=64, double-buffered prefetch, gload_lds staging ----------
// MODE 0: offset q-GEMM (B = v_t K-PANELS [480][1568][8], dst fp32 partials, split-K)
// MODE 1: deform GEMM  (B = sp panels, dst d_t K-PANELS [96][6272][8] +bias)
// MODE 2: conv1 s2 (B = d_t panels; PART fp32 NHWC partials), XCD m-fastest swizzle
// MODE 3: conv2 (B = h_t panels [64][1568][8]; PART fp32 partials), XCD m-fastest swizzle
template<int MODE, int BM, int BN, int WGM, int AO, int CIN, int KSPLIT,
         int NVALID, int IH, int IW, int OW, int STRIDE, int PART>
__global__ __launch_bounds__(256) void gemm_k(const short* __restrict__ Ap,
                                              const short* __restrict__ Bp,
                                              const float* __restrict__ bias,
                                              void* __restrict__ dst,
                                              const short* __restrict__ zp) {
  constexpr int WGN = 4 / WGM;
  constexpr int WM = BM / WGM, WN = BN / WGN;
  constexpr int MF = WM / 16, NF = WN / 16;
  constexpr int CHA = BM * 8, CHT = (BM + BN) * 8;
  constexpr int NT = KSPLIT / 64;

  __shared__ __align__(16) short SM[2][CHT * 8];

  const int tid = threadIdx.x;
  const int lane = tid & 63, wid = tid >> 6;
  const int wm = wid / WGN, wn = wid % WGN;
  int bx = blockIdx.x, by = blockIdx.y;
  if constexpr (MODE == 1) {
    // bijective XCD swizzle, nwg = 588 = 8*73 + 4; m-fastest within XCD chunk
    int bid = by * 98 + bx;
    int xcd = bid & 7, idx = bid >> 3;
    constexpr int q = 73, r = 4;
    int wg = (xcd < r ? xcd * (q + 1) : r * (q + 1) + (xcd - r) * q) + idx;
    by = wg % 6; bx = wg / 6;
  }
  if constexpr (MODE == 2) {
    // 200 blocks per z-slice = 8*25 exact; m-fastest (8 m-tiles share d_t window)
    int bid = by * 25 + bx;
    int swz = (bid & 7) * 25 + (bid >> 3);
    by = swz % 8; bx = swz / 8;
  }
  if constexpr (MODE == 3) {
    // 300 blocks per z-slice = 8*37 + 4; bijective, m-fastest (12 m-tiles share h_t)
    int bid = by * 25 + bx;
    int xcd = bid & 7, idx = bid >> 3;
    constexpr int q = 37, r = 4;
    int wg = (xcd < r ? xcd * (q + 1) : r * (q + 1) + (xcd - r) * q) + idx;
    by = wg % 12; bx = wg / 12;
  }
  const int n0 = bx * BN, m0 = by * BM;
  const int ts = blockIdx.z;
  const int kbeg = ts * KSPLIT;
  const int lrow = lane & 15, lkg = lane >> 4;

  v4f acc[MF][NF];
#pragma unroll
  for (int i = 0; i < MF; i++)
#pragma unroll
    for (int j = 0; j < NF; j++) acc[i][j] = (v4f){0.f, 0.f, 0.f, 0.f};

  auto stage = [&](int k, int buf) {
#pragma unroll
    for (int it = 0; it < CHT / 256; it++) {
      int ch = it * 256 + tid;
      const short* src;
      if (ch < CHA) {
        int kg = ch / BM, row = ch % BM;
        src = Ap + ((size_t)((k >> 3) + kg) * AO + m0 + row) * 8;
      } else {
        int bch = ch - CHA;
        int kg = bch / BN, col = bch % BN;
        int gk = k + kg * 8;
        int n = n0 + col;
        if constexpr (MODE == 0) {
          src = (n < NVALID) ? Bp + ((size_t)(gk >> 3) * 1568 + n) * 8 : zp;
        } else if constexpr (MODE == 1) {
          src = Bp + ((size_t)(gk >> 3) * 6272 + n) * 8;
        } else {
          int tap = gk / CIN, cc = gk % CIN;
          int b = n / (OW * OW), rem = n % (OW * OW);
          int oy = rem / OW, ox = rem % OW;
          int py = oy * STRIDE + tap / 3 - 1, px = ox * STRIDE + tap % 3 - 1;
          src = (n < NVALID && py >= 0 && py < IH && px >= 0 && px < IW)
                  ? Bp + ((size_t)(cc >> 3) * (8 * IH * IW) + (b * IH + py) * IW + px) * 8
                  : zp;
        }
      }
      gload16(src, &SM[buf][(size_t)(it * 256 + (tid & ~63)) * 8]);
    }
  };

  stage(kbeg, 0);
  __syncthreads();
  int buf = 0;
  for (int t = 0; t < NT; ++t) {
    if (t + 1 < NT) stage(kbeg + (t + 1) * 64, buf ^ 1);
    v8s af[2][MF], bfv[2][NF];
#pragma unroll
    for (int s = 0; s < 2; s++) {
#pragma unroll
      for (int mf = 0; mf < MF; mf++)
        af[s][mf] = *(const v8s*)(&SM[buf][(size_t)((s * 4 + lkg) * BM + wm * WM + mf * 16 + lrow) * 8]);
#pragma unroll
      for (int nf = 0; nf < NF; nf++)
        bfv[s][nf] = *(const v8s*)(&SM[buf][(size_t)(CHA + (s * 4 + lkg) * BN + wn * WN + nf * 16 + lrow) * 8]);
    }
#pragma unroll
    for (int s = 0; s < 2; s++)
#pragma unroll
      for (int mf = 0; mf < MF; mf++)
#pragma unroll
        for (int nf = 0; nf < NF; nf++)
          acc[mf][nf] = __builtin_amdgcn_mfma_f32_16x16x32_bf16(af[s][mf], bfv[s][nf], acc[mf][nf], 0, 0, 0);
    __syncthreads();
    buf ^= 1;
  }

#pragma unroll
  for (int mf = 0; mf < MF; mf++) {
    int gm = m0 + wm * WM + mf * 16 + lkg * 4;
#pragma unroll
    for (int nf = 0; nf < NF; nf++) {
      int gn = n0 + wn * WN + nf * 16 + lrow;
      v4f a4 = acc[mf][nf];
      if constexpr (MODE == 0) {
        float* part = (float*)dst;
        if (gn < NVALID) {
#pragma unroll
          for (int r = 0; r < 4; r++)
            part[((size_t)ts * AO + gm + r) * 1568 + gn] = a4[r];
        }
      } else if constexpr (MODE == 1) {
        short* dt = (short*)dst;     // d_t K-PANELS [96][6272][8]
        v4s v;
#pragma unroll
        for (int r = 0; r < 4; r++) v[r] = f2bf(a4[r] + bias[gm + r]);
        *(v4s*)(dt + ((size_t)(gm >> 3) * 6272 + gn) * 8 + (gm & 7)) = v;
      } else if constexpr (MODE == 2) {
        if (gn < NVALID) {
          float* pd = (float*)dst;
          *(v4f*)(pd + ((size_t)ts * 1568 + gn) * 512 + gm) = a4;
        }
      } else {
        if (gn < NVALID) {
          float* pd = (float*)dst;
#pragma unroll
          for (int r = 0; r < 4; r++)
            pd[((size_t)(ts * 768) + gm + r) * 1568 + gn] = a4[r];
        }
      }
    }
  }
}

// ---------- offset gather-reduce: offs[b][18][28][28] from q partials ----------
__global__ __launch_bounds__(256) void reduce_off2_k(const float* __restrict__ part,
                                                     const float* __restrict__ boff,
                                                     float* __restrict__ offs) {
  int i = blockIdx.x * 256 + threadIdx.x;
  if (i >= 8 * 18 * 784) return;
  int b = i / (18 * 784), r = i % (18 * 784);
  int o = r / 784, yx = r % 784;
  int y = yx / 28, x = yx % 28;
  float s = boff[o];
#pragma unroll
  for (int tap = 0; tap < 9; tap++) {
    int py = y + tap / 3 - 1, px = x + tap % 3 - 1;
    if (py >= 0 && py < 28 && px >= 0 && px < 28) {
      int n = b * 196 + (py >> 1) * 14 + (px >> 1);
      int m = o * 9 + tap;
#pragma unroll
      for (int z = 0; z < 4; z++)
        s += part[((size_t)z * 192 + m) * 1568 + n];
    }
  }
  offs[i] = s;
}

// ---------- conv1 split-K(3) reduce: partials [3][1568][512] -> h_t K-PANELS [64][1568][8] ----------
__global__ __launch_bounds__(256) void reduce_c1_k(const float* __restrict__ part,
                                                   const float* __restrict__ b1,
                                                   short* __restrict__ h_t) {
  int i = blockIdx.x * 256 + threadIdx.x;
  if (i >= 1568 * 128) return;
  int n = i >> 7, o4 = (i & 127) * 4;
  v4f s0 = *(const v4f*)(part + ((size_t)n) * 512 + o4);
  v4f s1 = *(const v4f*)(part + ((size_t)(1568 + n)) * 512 + o4);
  v4f s2 = *(const v4f*)(part + ((size_t)(3136 + n)) * 512 + o4);
  v4f bb = *(const v4f*)(b1 + o4);
  v4s v;
#pragma unroll
  for (int r = 0; r < 4; r++) v[r] = f2bf(fmaxf(s0[r] + s1[r] + s2[r] + bb[r], 0.f));
  *(v4s*)(h_t + ((size_t)(o4 >> 3) * 1568 + n) * 8 + (o4 & 7)) = v;
}

// ---------- conv2 split-K(3) reduce: partials [3][768][1568] -> out fp32 NCHW (+bias) ----------
__global__ __launch_bounds__(256) void reduce_c2_k(const float* __restrict__ part,
                                                   const float* __restrict__ b2,
                                                   float* __restrict__ out) {
  int i = blockIdx.x * 256 + threadIdx.x;
  if (i >= 768 * 392) return;
  int m = i / 392, n4 = (i % 392) * 4;
  v4f s0 = *(const v4f*)(part + (size_t)m * 1568 + n4);
  v4f s1 = *(const v4f*)(part + (size_t)(768 + m) * 1568 + n4);
  v4f s2 = *(const v4f*)(part + (size_t)(1536 + m) * 1568 + n4);
  float bv = b2[m];
  int b = n4 / 196, p = n4 % 196;
  v4f o;
#pragma unroll
  for (int r = 0; r < 4; r++) o[r] = s0[r] + s1[r] + s2[r] + bv;
  *(v4f*)(out + ((size_t)(b * 768 + m)) * 196 + p) = o;
}

// ---------- bilinear sampling: batch-pinned XCD, full-thread blocks (r15) ----------
__global__ __launch_bounds__(256) void sample_k(const short* __restrict__ cnn_t,
                                                const float* __restrict__ offs,
                                                short* __restrict__ sp) {
  int bid = blockIdx.x;
  int b = bid & 7;
  int r = bid >> 3;            // tap*25 + j
  int tap = r / 25, j = r % 25;
  int item = j * 256 + threadIdx.x;
  if (item >= 6272) return;
  int cg = item / 784;
  int yx = item - cg * 784;
  int y = yx / 28, x = yx % 28;
  float dy = offs[((size_t)b * 18 + tap * 2 + 0) * 784 + yx];
  float dx = offs[((size_t)b * 18 + tap * 2 + 1) * 784 + yx];
  float py = (float)(y + tap / 3 - 1) + dy;
  float px = (float)(x + tap % 3 - 1) + dx;
  float fy = floorf(py), fx = floorf(px);
  float ly = py - fy, lx = px - fx;
  int y0 = (int)fy, x0 = (int)fx;
  int y1 = y0 + 1, x1 = x0 + 1;
  float vy0 = (y0 >= 0 && y0 < 28) ? 1.f : 0.f;
  float vy1 = (y1 >= 0 && y1 < 28) ? 1.f : 0.f;
  float vx0 = (x0 >= 0 && x0 < 28) ? 1.f : 0.f;
  float vx1 = (x1 >= 0 && x1 < 28) ? 1.f : 0.f;
  float w00 = (1.f - ly) * (1.f - lx) * vy0 * vx0;
  float w01 = (1.f - ly) * lx * vy0 * vx1;
  float w10 = ly * (1.f - lx) * vy1 * vx0;
  float w11 = ly * lx * vy1 * vx1;
  int cy0 = min(max(y0, 0), 27), cy1 = min(max(y1, 0), 27);
  int cx0 = min(max(x0, 0), 27), cx1 = min(max(x1, 0), 27);
  int c0 = cg * 12;
  const short* base = cnn_t + (size_t)b * 784 * 768 + c0 * 8;
  const short* p00 = base + (size_t)(cy0 * 28 + cx0) * 768;
  const short* p01 = base + (size_t)(cy0 * 28 + cx1) * 768;
  const short* p10 = base + (size_t)(cy1 * 28 + cx0) * 768;
  const short* p11 = base + (size_t)(cy1 * 28 + cx1) * 768;
  short* op = sp + ((size_t)(tap * 96 + c0) * 6272 + b * 784 + yx) * 8;
#pragma unroll 4
  for (int i = 0; i < 12; ++i) {
    v8s a = *(const v8s*)(p00 + i * 8);
    v8s bb = *(const v8s*)(p01 + i * 8);
    v8s c = *(const v8s*)(p10 + i * 8);
    v8s d = *(const v8s*)(p11 + i * 8);
    v8s o;
#pragma unroll
    for (int jj = 0; jj < 8; jj++) {
      float v = w00 * bf2f(a[jj]) + w01 * bf2f(bb[jj]) + w10 * bf2f(c[jj]) + w11 * bf2f(d[jj]);
      o[jj] = f2bf(v);
    }
    *(v8s*)op = o;
    op += (size_t)6272 * 8;
  }
}

// ---------- launch ----------
extern "C" void kernel_launch(void* const* d_in, const int* in_sizes, int n_in,
                              void* d_out, int out_size, void* d_ws, size_t ws_size,
                              hipStream_t stream) {
  const float* cnn   = (const float*)d_in[0];
  const float* vit   = (const float*)d_in[1];
  const float* w_off = (const float*)d_in[2];
  const float* b_off = (const float*)d_in[3];
  const float* w_def = (const float*)d_in[4];
  const float* b_def = (const float*)d_in[5];
  const float* w1    = (const float*)d_in[6];
  const float* b1    = (const float*)d_in[7];
  const float* w2    = (const float*)d_in[8];
  const float* b2    = (const float*)d_in[9];
  float* out = (float*)d_out;
  char* ws = (char*)d_ws;

  short* wdef_p  = (short*)(ws + 0);          // 10,616,832
  short* w1_p    = (short*)(ws + 10616832);   //  7,077,888
  short* w2_p    = (short*)(ws + 17694720);   //  7,077,888
  short* woff2_p = (short*)(ws + 24772608);   //  1,474,560
  short* v_t     = (short*)(ws + 26247168);   // 12,042,240 (K-panels [480][1568][8])
  float* offs    = (float*)(ws + 38289408);   //    451,584
  float* part    = (float*)(ws + 38740992);   //  4,816,896 (dead after reduce_off2)
  short* sp      = (short*)(ws + 38740992);   // 86,704,128 (aliases part; dead after deform)
  float* part1   = (float*)(ws + 38740992);   //  9,633,792 (aliases sp; conv1 partials, z=3)
  float* part2   = (float*)(ws + 48374784);   // 14,450,688 (conv2 partials, z=3)
  short* d_t     = (short*)(ws + 125445120);  //  9,633,792 (K-panels [96][6272][8])
  short* h_t     = (short*)(ws + 135078912);  //  1,605,632 (K-panels [64][1568][8])
  short* cnn_t   = (short*)(ws + 136684544);  //  9,633,792 (NHWC)
  short* zp      = (short*)(ws + 146318336);  // 256 zero page
  // total 146,318,592 bytes

  dim3 blk(256);
  // fused weight preps + transposes + zp clear (one launch, 56,617 blocks)
  prep_fused_k<<<56617, blk, 0, stream>>>(w_def, w1, w2, w_off, vit, cnn,
                                          wdef_p, w1_p, w2_p, woff2_p, v_t, cnn_t, zp);

  // offset q-GEMM: q[o*9+tap][n14], split-K x4 -> partials (B = v_t panels, coalesced)
  gemm_k<0, 64, 64, 2, 192, 3840, 960, 1568, 14, 14, 14, 1, 0>
      <<<dim3(25, 3, 4), blk, 0, stream>>>(woff2_p, v_t, nullptr, part, zp);
  // gather-reduce -> offs[b][18][28][28]
  reduce_off2_k<<<441, blk, 0, stream>>>(part, b_off, offs);

  // bilinear sampling -> sp panels (batch-pinned XCD, 1800 full-thread blocks)
  sample_k<<<1800, blk, 0, stream>>>(cnn_t, offs, sp);

  // deformable conv GEMM -> d_t K-panels, 128x64 tiles, 588 blocks, m-fastest XCD order
  gemm_k<1, 128, 64, 2, 768, 768, 6912, 6272, 28, 28, 28, 1, 0>
      <<<dim3(98, 6, 1), blk, 0, stream>>>(wdef_p, sp, b_def, d_t, zp);

  // conv1 stride 2, split-K x3 (XCD m-fastest, B = d_t panels coalesced) -> partials -> reduce
  gemm_k<2, 64, 64, 2, 512, 768, 2304, 1568, 28, 28, 14, 2, 1>
      <<<dim3(25, 8, 3), blk, 0, stream>>>(w1_p, d_t, b1, part1, zp);
  reduce_c1_k<<<784, blk, 0, stream>>>(part1, b1, h_t);

  // conv2 split-K x3 (XCD m-fastest, B = h_t panels coalesced) -> partials -> reduce
  gemm_k<3, 64, 64, 2, 768, 512, 1536, 1568, 14, 14, 14, 1, 1>
      <<<dim3(25, 12, 3), blk, 0, stream>>>(w2_p, h_t, b2, part2, zp);
  reduce_c2_k<<<1176, blk, 0, stream>>>(part2, b2, out);
}